// Round 1
// baseline (3897.055 us; speedup 1.0000x reference)
//
#include <hip/hip_runtime.h>
#include <math.h>

#define N_NODES 100000
#define HDIM    128
#define ODIM    40

// ---------------------------------------------------------------------------
// Degree counts: one atomicAdd per edge.
// ---------------------------------------------------------------------------
__global__ __launch_bounds__(256) void count_deg_kernel(
    const int* __restrict__ dst, float* __restrict__ counts, int E)
{
    int e = blockIdx.x * 256 + threadIdx.x;
    if (e < E) atomicAdd(counts + dst[e], 1.0f);
}

// ---------------------------------------------------------------------------
// Scatter-add of source features into accumulator: 32 lanes per edge,
// float4 gather + 4 scalar float atomics.
// ---------------------------------------------------------------------------
__global__ __launch_bounds__(256) void scatter_add_kernel(
    const int* __restrict__ src, const int* __restrict__ dst,
    const float* __restrict__ feat, float* __restrict__ accum, int E)
{
    int t = blockIdx.x * 256 + threadIdx.x;
    int e = t >> 5;               // 32 threads per edge
    if (e >= E) return;
    int c = (t & 31) << 2;        // float offset 0..124
    int s = src[e];
    int d = dst[e];
    const float4 v = *reinterpret_cast<const float4*>(feat + (size_t)s * HDIM + c);
    float* p = accum + (size_t)d * HDIM + c;
    atomicAdd(p + 0, v.x);
    atomicAdd(p + 1, v.y);
    atomicAdd(p + 2, v.z);
    atomicAdd(p + 3, v.w);
}

// ---------------------------------------------------------------------------
// Fused SAGE linear: out = [relu]( (Ain/count) @ Wl + bias + Bin @ Wr )
//   counts == nullptr -> no scaling of Ain
//   Bin/Wr == nullptr -> skip the second matmul (plain linear)
// Block: 256 threads, 32 rows x 128 cols tile. Thread computes 4 rows x 4 cols.
// ---------------------------------------------------------------------------
#define FMA4(A_, s_, W_) { (A_).x += (s_) * (W_).x; (A_).y += (s_) * (W_).y; \
                           (A_).z += (s_) * (W_).z; (A_).w += (s_) * (W_).w; }

__global__ __launch_bounds__(256) void sage_gemm_kernel(
    const float* __restrict__ Ain, const float* __restrict__ counts,
    const float* __restrict__ Bin,
    const float* __restrict__ Wl, const float* __restrict__ Wr,
    const float* __restrict__ bias, float* __restrict__ out, int do_relu)
{
    __shared__ float sA[32][HDIM];
    __shared__ float sB[32][HDIM];
    __shared__ float sinv[32];
    const int tid  = threadIdx.x;
    const int base = blockIdx.x * 32;

    if (tid < 32) {
        float c = 1.0f;
        if (counts) { c = counts[base + tid]; if (c < 1.0f) c = 1.0f; }
        sinv[tid] = 1.0f / c;
    }
    __syncthreads();

    const bool haveB = (Bin != nullptr);
    for (int it = 0; it < 4; ++it) {
        int f   = it * 256 + tid;     // float4 chunk id 0..1023
        int row = f >> 5;             // 32 float4 chunks per row
        int cc  = (f & 31) << 2;
        float4 a = *reinterpret_cast<const float4*>(Ain + (size_t)(base + row) * HDIM + cc);
        float s = sinv[row];
        a.x *= s; a.y *= s; a.z *= s; a.w *= s;
        *reinterpret_cast<float4*>(&sA[row][cc]) = a;
        if (haveB) {
            *reinterpret_cast<float4*>(&sB[row][cc]) =
                *reinterpret_cast<const float4*>(Bin + (size_t)(base + row) * HDIM + cc);
        }
    }
    __syncthreads();

    const int jg   = tid & 31;   // col group
    const int rg   = tid >> 5;   // row group
    const int col0 = jg << 2;
    const int row0 = rg << 2;

    float4 acc0 = {0.f,0.f,0.f,0.f}, acc1 = {0.f,0.f,0.f,0.f};
    float4 acc2 = {0.f,0.f,0.f,0.f}, acc3 = {0.f,0.f,0.f,0.f};

    // phase 1: (Ain/count) @ Wl
    for (int k = 0; k < HDIM; k += 4) {
        float4 w0 = *reinterpret_cast<const float4*>(Wl + (size_t)(k + 0) * HDIM + col0);
        float4 w1 = *reinterpret_cast<const float4*>(Wl + (size_t)(k + 1) * HDIM + col0);
        float4 w2 = *reinterpret_cast<const float4*>(Wl + (size_t)(k + 2) * HDIM + col0);
        float4 w3 = *reinterpret_cast<const float4*>(Wl + (size_t)(k + 3) * HDIM + col0);
        float4 a0 = *reinterpret_cast<const float4*>(&sA[row0 + 0][k]);
        float4 a1 = *reinterpret_cast<const float4*>(&sA[row0 + 1][k]);
        float4 a2 = *reinterpret_cast<const float4*>(&sA[row0 + 2][k]);
        float4 a3 = *reinterpret_cast<const float4*>(&sA[row0 + 3][k]);
        FMA4(acc0, a0.x, w0) FMA4(acc0, a0.y, w1) FMA4(acc0, a0.z, w2) FMA4(acc0, a0.w, w3)
        FMA4(acc1, a1.x, w0) FMA4(acc1, a1.y, w1) FMA4(acc1, a1.z, w2) FMA4(acc1, a1.w, w3)
        FMA4(acc2, a2.x, w0) FMA4(acc2, a2.y, w1) FMA4(acc2, a2.z, w2) FMA4(acc2, a2.w, w3)
        FMA4(acc3, a3.x, w0) FMA4(acc3, a3.y, w1) FMA4(acc3, a3.z, w2) FMA4(acc3, a3.w, w3)
    }

    // phase 2: Bin @ Wr
    if (Wr != nullptr) {
        for (int k = 0; k < HDIM; k += 4) {
            float4 w0 = *reinterpret_cast<const float4*>(Wr + (size_t)(k + 0) * HDIM + col0);
            float4 w1 = *reinterpret_cast<const float4*>(Wr + (size_t)(k + 1) * HDIM + col0);
            float4 w2 = *reinterpret_cast<const float4*>(Wr + (size_t)(k + 2) * HDIM + col0);
            float4 w3 = *reinterpret_cast<const float4*>(Wr + (size_t)(k + 3) * HDIM + col0);
            float4 a0 = *reinterpret_cast<const float4*>(&sB[row0 + 0][k]);
            float4 a1 = *reinterpret_cast<const float4*>(&sB[row0 + 1][k]);
            float4 a2 = *reinterpret_cast<const float4*>(&sB[row0 + 2][k]);
            float4 a3 = *reinterpret_cast<const float4*>(&sB[row0 + 3][k]);
            FMA4(acc0, a0.x, w0) FMA4(acc0, a0.y, w1) FMA4(acc0, a0.z, w2) FMA4(acc0, a0.w, w3)
            FMA4(acc1, a1.x, w0) FMA4(acc1, a1.y, w1) FMA4(acc1, a1.z, w2) FMA4(acc1, a1.w, w3)
            FMA4(acc2, a2.x, w0) FMA4(acc2, a2.y, w1) FMA4(acc2, a2.z, w2) FMA4(acc2, a2.w, w3)
            FMA4(acc3, a3.x, w0) FMA4(acc3, a3.y, w1) FMA4(acc3, a3.z, w2) FMA4(acc3, a3.w, w3)
        }
    }

    float4 bv = *reinterpret_cast<const float4*>(bias + col0);
    acc0.x += bv.x; acc0.y += bv.y; acc0.z += bv.z; acc0.w += bv.w;
    acc1.x += bv.x; acc1.y += bv.y; acc1.z += bv.z; acc1.w += bv.w;
    acc2.x += bv.x; acc2.y += bv.y; acc2.z += bv.z; acc2.w += bv.w;
    acc3.x += bv.x; acc3.y += bv.y; acc3.z += bv.z; acc3.w += bv.w;

    if (do_relu) {
        acc0.x = fmaxf(acc0.x, 0.f); acc0.y = fmaxf(acc0.y, 0.f); acc0.z = fmaxf(acc0.z, 0.f); acc0.w = fmaxf(acc0.w, 0.f);
        acc1.x = fmaxf(acc1.x, 0.f); acc1.y = fmaxf(acc1.y, 0.f); acc1.z = fmaxf(acc1.z, 0.f); acc1.w = fmaxf(acc1.w, 0.f);
        acc2.x = fmaxf(acc2.x, 0.f); acc2.y = fmaxf(acc2.y, 0.f); acc2.z = fmaxf(acc2.z, 0.f); acc2.w = fmaxf(acc2.w, 0.f);
        acc3.x = fmaxf(acc3.x, 0.f); acc3.y = fmaxf(acc3.y, 0.f); acc3.z = fmaxf(acc3.z, 0.f); acc3.w = fmaxf(acc3.w, 0.f);
    }

    *reinterpret_cast<float4*>(out + (size_t)(base + row0 + 0) * HDIM + col0) = acc0;
    *reinterpret_cast<float4*>(out + (size_t)(base + row0 + 1) * HDIM + col0) = acc1;
    *reinterpret_cast<float4*>(out + (size_t)(base + row0 + 2) * HDIM + col0) = acc2;
    *reinterpret_cast<float4*>(out + (size_t)(base + row0 + 3) * HDIM + col0) = acc3;
}

// ---------------------------------------------------------------------------
// Final: z = t @ Wf2 + bf2  (128 -> 40), then row-wise log_softmax.
// Block: 256 threads, 32 nodes per block.
// ---------------------------------------------------------------------------
__global__ __launch_bounds__(256) void mlp_softmax_kernel(
    const float* __restrict__ t, const float* __restrict__ Wf2,
    const float* __restrict__ bf2, float* __restrict__ out)
{
    __shared__ float sT[32][HDIM];      // 16 KB
    __shared__ float sW[HDIM * ODIM];   // 20 KB
    __shared__ float sb[ODIM];
    __shared__ float sZ[32][ODIM];      // 5 KB

    const int tid  = threadIdx.x;
    const int base = blockIdx.x * 32;

    for (int i = tid; i < HDIM * ODIM; i += 256) sW[i] = Wf2[i];
    if (tid < ODIM) sb[tid] = bf2[tid];
    for (int it = 0; it < 4; ++it) {
        int f   = it * 256 + tid;
        int row = f >> 5;
        int cc  = (f & 31) << 2;
        *reinterpret_cast<float4*>(&sT[row][cc]) =
            *reinterpret_cast<const float4*>(t + (size_t)(base + row) * HDIM + cc);
    }
    __syncthreads();

    // 32 nodes * 40 outputs = 1280 dot products
    for (int it = 0; it < 5; ++it) {
        int idx = it * 256 + tid;
        int n = idx / ODIM;
        int o = idx - n * ODIM;
        float s = sb[o];
        #pragma unroll 8
        for (int k = 0; k < HDIM; ++k) s += sT[n][k] * sW[k * ODIM + o];
        sZ[n][o] = s;
    }
    __syncthreads();

    if (tid < 32) {
        float m = -INFINITY;
        #pragma unroll
        for (int o = 0; o < ODIM; ++o) m = fmaxf(m, sZ[tid][o]);
        float sum = 0.f;
        #pragma unroll
        for (int o = 0; o < ODIM; ++o) sum += expf(sZ[tid][o] - m);
        float lse = logf(sum) + m;
        size_t off = (size_t)(base + tid) * ODIM;
        #pragma unroll
        for (int o = 0; o < ODIM; ++o) out[off + o] = sZ[tid][o] - lse;
    }
}

// ---------------------------------------------------------------------------
extern "C" void kernel_launch(void* const* d_in, const int* in_sizes, int n_in,
                              void* d_out, int out_size, void* d_ws, size_t ws_size,
                              hipStream_t stream) {
    const float* x   = (const float*)d_in[0];
    const int*   ei  = (const int*)d_in[1];
    const int E = in_sizes[1] / 2;
    const int* src = ei;
    const int* dst = ei + E;

    const float* W1l = (const float*)d_in[2];
    const float* b1  = (const float*)d_in[3];
    const float* W1r = (const float*)d_in[4];
    const float* W2l = (const float*)d_in[5];
    const float* b2  = (const float*)d_in[6];
    const float* W2r = (const float*)d_in[7];
    const float* W3l = (const float*)d_in[8];
    const float* b3  = (const float*)d_in[9];
    const float* W3r = (const float*)d_in[10];
    const float* Wf1 = (const float*)d_in[11];
    const float* bf1 = (const float*)d_in[12];
    const float* Wf2 = (const float*)d_in[13];
    const float* bf2 = (const float*)d_in[14];

    float* out = (float*)d_out;
    float* h3  = out + (size_t)N_NODES * ODIM;      // tuple part 2: h [N,128]

    // Workspace layout (floats): counts | A (aggr / t) | F (features)
    float* ws     = (float*)d_ws;
    float* counts = ws;                              // 100000 floats
    float* A      = ws + 131072;                     // 12.8M floats (512KB-aligned ofs)
    float* F      = A + (size_t)N_NODES * HDIM;      // 12.8M floats

    const size_t featBytes = (size_t)N_NODES * HDIM * sizeof(float);
    const int gemmGrid    = N_NODES / 32;            // 3125
    const int scatterGrid = (E * 32 + 255) / 256;    // 80000
    const int countGrid   = (E + 255) / 256;         // 2500

    // degree counts
    hipMemsetAsync(counts, 0, N_NODES * sizeof(float), stream);
    count_deg_kernel<<<countGrid, 256, 0, stream>>>(dst, counts, E);

    // ---- layer 1 ----
    hipMemsetAsync(A, 0, featBytes, stream);
    scatter_add_kernel<<<scatterGrid, 256, 0, stream>>>(src, dst, x, A, E);
    sage_gemm_kernel<<<gemmGrid, 256, 0, stream>>>(A, counts, x, W1l, W1r, b1, F, 1);

    // ---- layer 2 (in-place on F: rows staged to LDS before writeback) ----
    hipMemsetAsync(A, 0, featBytes, stream);
    scatter_add_kernel<<<scatterGrid, 256, 0, stream>>>(src, dst, F, A, E);
    sage_gemm_kernel<<<gemmGrid, 256, 0, stream>>>(A, counts, F, W2l, W2r, b2, F, 1);

    // ---- layer 3 (no relu, h3 -> d_out tail) ----
    hipMemsetAsync(A, 0, featBytes, stream);
    scatter_add_kernel<<<scatterGrid, 256, 0, stream>>>(src, dst, F, A, E);
    sage_gemm_kernel<<<gemmGrid, 256, 0, stream>>>(A, counts, F, W3l, W3r, b3, h3, 0);

    // ---- MLP head: t = relu(h3 @ Wf1 + bf1) into A, then Wf2 + log_softmax ----
    sage_gemm_kernel<<<gemmGrid, 256, 0, stream>>>(h3, nullptr, nullptr, Wf1, nullptr, bf1, A, 1);
    mlp_softmax_kernel<<<gemmGrid, 256, 0, stream>>>(A, Wf2, bf2, out);
}

// Round 2
// 991.131 us; speedup vs baseline: 3.9319x; 3.9319x over previous
//
#include <hip/hip_runtime.h>
#include <math.h>

#define N_NODES 100000
#define HDIM    128
#define ODIM    40
#define NBLK    ((N_NODES + 255) / 256)   // 391

// ---------------------------------------------------------------------------
// CSR build: counting sort of edges by dst.
// ---------------------------------------------------------------------------
__global__ __launch_bounds__(256) void count_deg_kernel(
    const int* __restrict__ dst, int* __restrict__ ic, int E)
{
    int e = blockIdx.x * 256 + threadIdx.x;
    if (e < E) atomicAdd(ic + dst[e], 1);
}

__global__ __launch_bounds__(256) void block_sum_kernel(
    const int* __restrict__ ic, int* __restrict__ bs, int n)
{
    __shared__ int sm[256];
    int t = threadIdx.x;
    int i = blockIdx.x * 256 + t;
    sm[t] = (i < n) ? ic[i] : 0;
    __syncthreads();
    for (int s = 128; s > 0; s >>= 1) {
        if (t < s) sm[t] += sm[t + s];
        __syncthreads();
    }
    if (t == 0) bs[blockIdx.x] = sm[0];
}

// single block, exclusive scan of nb (<512) block sums, in place
__global__ __launch_bounds__(512) void scan_bs_kernel(int* __restrict__ bs, int nb)
{
    __shared__ int sm[512];
    int t = threadIdx.x;
    sm[t] = (t < nb) ? bs[t] : 0;
    __syncthreads();
    for (int off = 1; off < 512; off <<= 1) {
        int v = (t >= off) ? sm[t - off] : 0;
        __syncthreads();
        sm[t] += v;
        __syncthreads();
    }
    if (t < nb) bs[t] = (t == 0) ? 0 : sm[t - 1];
}

// per-element exclusive scan within block + block base -> start positions
__global__ __launch_bounds__(256) void scan_block_kernel(
    const int* __restrict__ ic, const int* __restrict__ bs,
    int* __restrict__ pc, int n)
{
    __shared__ int sm[256];
    int t = threadIdx.x;
    int i = blockIdx.x * 256 + t;
    int v = (i < n) ? ic[i] : 0;
    sm[t] = v;
    __syncthreads();
    for (int off = 1; off < 256; off <<= 1) {
        int u = (t >= off) ? sm[t - off] : 0;
        __syncthreads();
        sm[t] += u;
        __syncthreads();
    }
    if (i < n) pc[i] = bs[blockIdx.x] + sm[t] - v;   // exclusive
}

// fill: pc (start cursors) atomically bumped; afterwards pc[n] == end-of-list.
__global__ __launch_bounds__(256) void fill_kernel(
    const int* __restrict__ src, const int* __restrict__ dst,
    int* __restrict__ pc, int* __restrict__ cs, int E)
{
    int e = blockIdx.x * 256 + threadIdx.x;
    if (e < E) {
        int p = atomicAdd(pc + dst[e], 1);
        cs[p] = src[e];
    }
}

// ---------------------------------------------------------------------------
// Fused SAGE layer: per block of 32 nodes,
//   sA[row] = mean of feat[neighbors(row)]   (CSR gather, wave-cooperative)
//   sB[row] = feat[row]
//   out = [relu]( sA @ Wl + bias + sB @ Wr )
// If cs == nullptr: plain linear, sA[row] = feat[row], Wr skipped.
// ---------------------------------------------------------------------------
#define FMA4(A_, s_, W_) { (A_).x += (s_) * (W_).x; (A_).y += (s_) * (W_).y; \
                           (A_).z += (s_) * (W_).z; (A_).w += (s_) * (W_).w; }

__global__ __launch_bounds__(256) void sage_fused_kernel(
    const float* __restrict__ feat,
    const int* __restrict__ cs, const int* __restrict__ pc, const int* __restrict__ ic,
    const float* __restrict__ Wl, const float* __restrict__ Wr,
    const float* __restrict__ bias, float* __restrict__ out, int do_relu)
{
    __shared__ float sA[32][HDIM];
    __shared__ float sB[32][HDIM];
    const int tid  = threadIdx.x;
    const int base = blockIdx.x * 32;
    const bool gather = (cs != nullptr);

    if (gather) {
        for (int it = 0; it < 4; ++it) {
            int f   = it * 256 + tid;
            int row = f >> 5;
            int cc  = (f & 31) << 2;
            *reinterpret_cast<float4*>(&sB[row][cc]) =
                *reinterpret_cast<const float4*>(feat + (size_t)(base + row) * HDIM + cc);
        }
        const int lane = tid & 63;
        const int wave = tid >> 6;
        for (int r8 = 0; r8 < 8; ++r8) {
            int row  = wave * 8 + r8;
            int node = base + row;
            int end  = pc[node];
            int deg  = ic[node];
            float2 acc = {0.f, 0.f};
            for (int j = end - deg; j < end; ++j) {
                int s = cs[j];
                float2 v = *reinterpret_cast<const float2*>(feat + (size_t)s * HDIM + lane * 2);
                acc.x += v.x; acc.y += v.y;
            }
            float inv = 1.0f / (float)(deg > 0 ? deg : 1);
            float2 r; r.x = acc.x * inv; r.y = acc.y * inv;
            *reinterpret_cast<float2*>(&sA[row][lane * 2]) = r;
        }
    } else {
        for (int it = 0; it < 4; ++it) {
            int f   = it * 256 + tid;
            int row = f >> 5;
            int cc  = (f & 31) << 2;
            *reinterpret_cast<float4*>(&sA[row][cc]) =
                *reinterpret_cast<const float4*>(feat + (size_t)(base + row) * HDIM + cc);
        }
    }
    __syncthreads();

    const int jg   = tid & 31;
    const int rg   = tid >> 5;
    const int col0 = jg << 2;
    const int row0 = rg << 2;

    float4 acc0 = {0.f,0.f,0.f,0.f}, acc1 = {0.f,0.f,0.f,0.f};
    float4 acc2 = {0.f,0.f,0.f,0.f}, acc3 = {0.f,0.f,0.f,0.f};

    for (int k = 0; k < HDIM; k += 4) {
        float4 w0 = *reinterpret_cast<const float4*>(Wl + (size_t)(k + 0) * HDIM + col0);
        float4 w1 = *reinterpret_cast<const float4*>(Wl + (size_t)(k + 1) * HDIM + col0);
        float4 w2 = *reinterpret_cast<const float4*>(Wl + (size_t)(k + 2) * HDIM + col0);
        float4 w3 = *reinterpret_cast<const float4*>(Wl + (size_t)(k + 3) * HDIM + col0);
        float4 a0 = *reinterpret_cast<const float4*>(&sA[row0 + 0][k]);
        float4 a1 = *reinterpret_cast<const float4*>(&sA[row0 + 1][k]);
        float4 a2 = *reinterpret_cast<const float4*>(&sA[row0 + 2][k]);
        float4 a3 = *reinterpret_cast<const float4*>(&sA[row0 + 3][k]);
        FMA4(acc0, a0.x, w0) FMA4(acc0, a0.y, w1) FMA4(acc0, a0.z, w2) FMA4(acc0, a0.w, w3)
        FMA4(acc1, a1.x, w0) FMA4(acc1, a1.y, w1) FMA4(acc1, a1.z, w2) FMA4(acc1, a1.w, w3)
        FMA4(acc2, a2.x, w0) FMA4(acc2, a2.y, w1) FMA4(acc2, a2.z, w2) FMA4(acc2, a2.w, w3)
        FMA4(acc3, a3.x, w0) FMA4(acc3, a3.y, w1) FMA4(acc3, a3.z, w2) FMA4(acc3, a3.w, w3)
    }

    if (Wr != nullptr) {
        for (int k = 0; k < HDIM; k += 4) {
            float4 w0 = *reinterpret_cast<const float4*>(Wr + (size_t)(k + 0) * HDIM + col0);
            float4 w1 = *reinterpret_cast<const float4*>(Wr + (size_t)(k + 1) * HDIM + col0);
            float4 w2 = *reinterpret_cast<const float4*>(Wr + (size_t)(k + 2) * HDIM + col0);
            float4 w3 = *reinterpret_cast<const float4*>(Wr + (size_t)(k + 3) * HDIM + col0);
            float4 a0 = *reinterpret_cast<const float4*>(&sB[row0 + 0][k]);
            float4 a1 = *reinterpret_cast<const float4*>(&sB[row0 + 1][k]);
            float4 a2 = *reinterpret_cast<const float4*>(&sB[row0 + 2][k]);
            float4 a3 = *reinterpret_cast<const float4*>(&sB[row0 + 3][k]);
            FMA4(acc0, a0.x, w0) FMA4(acc0, a0.y, w1) FMA4(acc0, a0.z, w2) FMA4(acc0, a0.w, w3)
            FMA4(acc1, a1.x, w0) FMA4(acc1, a1.y, w1) FMA4(acc1, a1.z, w2) FMA4(acc1, a1.w, w3)
            FMA4(acc2, a2.x, w0) FMA4(acc2, a2.y, w1) FMA4(acc2, a2.z, w2) FMA4(acc2, a2.w, w3)
            FMA4(acc3, a3.x, w0) FMA4(acc3, a3.y, w1) FMA4(acc3, a3.z, w2) FMA4(acc3, a3.w, w3)
        }
    }

    float4 bv = *reinterpret_cast<const float4*>(bias + col0);
    acc0.x += bv.x; acc0.y += bv.y; acc0.z += bv.z; acc0.w += bv.w;
    acc1.x += bv.x; acc1.y += bv.y; acc1.z += bv.z; acc1.w += bv.w;
    acc2.x += bv.x; acc2.y += bv.y; acc2.z += bv.z; acc2.w += bv.w;
    acc3.x += bv.x; acc3.y += bv.y; acc3.z += bv.z; acc3.w += bv.w;

    if (do_relu) {
        acc0.x = fmaxf(acc0.x, 0.f); acc0.y = fmaxf(acc0.y, 0.f); acc0.z = fmaxf(acc0.z, 0.f); acc0.w = fmaxf(acc0.w, 0.f);
        acc1.x = fmaxf(acc1.x, 0.f); acc1.y = fmaxf(acc1.y, 0.f); acc1.z = fmaxf(acc1.z, 0.f); acc1.w = fmaxf(acc1.w, 0.f);
        acc2.x = fmaxf(acc2.x, 0.f); acc2.y = fmaxf(acc2.y, 0.f); acc2.z = fmaxf(acc2.z, 0.f); acc2.w = fmaxf(acc2.w, 0.f);
        acc3.x = fmaxf(acc3.x, 0.f); acc3.y = fmaxf(acc3.y, 0.f); acc3.z = fmaxf(acc3.z, 0.f); acc3.w = fmaxf(acc3.w, 0.f);
    }

    *reinterpret_cast<float4*>(out + (size_t)(base + row0 + 0) * HDIM + col0) = acc0;
    *reinterpret_cast<float4*>(out + (size_t)(base + row0 + 1) * HDIM + col0) = acc1;
    *reinterpret_cast<float4*>(out + (size_t)(base + row0 + 2) * HDIM + col0) = acc2;
    *reinterpret_cast<float4*>(out + (size_t)(base + row0 + 3) * HDIM + col0) = acc3;
}

// ---------------------------------------------------------------------------
// Final: z = t @ Wf2 + bf2  (128 -> 40), then row-wise log_softmax.
// ---------------------------------------------------------------------------
__global__ __launch_bounds__(256) void mlp_softmax_kernel(
    const float* __restrict__ t, const float* __restrict__ Wf2,
    const float* __restrict__ bf2, float* __restrict__ out)
{
    __shared__ float sT[32][HDIM];
    __shared__ float sW[HDIM * ODIM];
    __shared__ float sb[ODIM];
    __shared__ float sZ[32][ODIM];

    const int tid  = threadIdx.x;
    const int base = blockIdx.x * 32;

    for (int i = tid; i < HDIM * ODIM; i += 256) sW[i] = Wf2[i];
    if (tid < ODIM) sb[tid] = bf2[tid];
    for (int it = 0; it < 4; ++it) {
        int f   = it * 256 + tid;
        int row = f >> 5;
        int cc  = (f & 31) << 2;
        *reinterpret_cast<float4*>(&sT[row][cc]) =
            *reinterpret_cast<const float4*>(t + (size_t)(base + row) * HDIM + cc);
    }
    __syncthreads();

    for (int it = 0; it < 5; ++it) {
        int idx = it * 256 + tid;
        int n = idx / ODIM;
        int o = idx - n * ODIM;
        float s = sb[o];
        #pragma unroll 8
        for (int k = 0; k < HDIM; ++k) s += sT[n][k] * sW[k * ODIM + o];
        sZ[n][o] = s;
    }
    __syncthreads();

    if (tid < 32) {
        float m = -INFINITY;
        #pragma unroll
        for (int o = 0; o < ODIM; ++o) m = fmaxf(m, sZ[tid][o]);
        float sum = 0.f;
        #pragma unroll
        for (int o = 0; o < ODIM; ++o) sum += expf(sZ[tid][o] - m);
        float lse = logf(sum) + m;
        size_t off = (size_t)(base + tid) * ODIM;
        #pragma unroll
        for (int o = 0; o < ODIM; ++o) out[off + o] = sZ[tid][o] - lse;
    }
}

// ---------------------------------------------------------------------------
extern "C" void kernel_launch(void* const* d_in, const int* in_sizes, int n_in,
                              void* d_out, int out_size, void* d_ws, size_t ws_size,
                              hipStream_t stream) {
    const float* x   = (const float*)d_in[0];
    const int*   ei  = (const int*)d_in[1];
    const int E = in_sizes[1] / 2;
    const int* src = ei;
    const int* dst = ei + E;

    const float* W1l = (const float*)d_in[2];
    const float* b1  = (const float*)d_in[3];
    const float* W1r = (const float*)d_in[4];
    const float* W2l = (const float*)d_in[5];
    const float* b2  = (const float*)d_in[6];
    const float* W2r = (const float*)d_in[7];
    const float* W3l = (const float*)d_in[8];
    const float* b3  = (const float*)d_in[9];
    const float* W3r = (const float*)d_in[10];
    const float* Wf1 = (const float*)d_in[11];
    const float* bf1 = (const float*)d_in[12];
    const float* Wf2 = (const float*)d_in[13];
    const float* bf2 = (const float*)d_in[14];

    float* out     = (float*)d_out;
    float* outTail = out + (size_t)N_NODES * ODIM;     // tuple part 2: h [N,128]

    // Workspace: | ic (100k int) | pc (100k int) | bs (1k int) | cs (E int) | F1 |
    int* ic = (int*)d_ws;
    int* pc = ic + 100352;
    int* bs = pc + 100352;
    int* cs = bs + 1024;
    float* F1 = (float*)(cs + ((E + 127) & ~127));

    const size_t featBytes = (size_t)N_NODES * HDIM * sizeof(float);
    const int gemmGrid = N_NODES / 32;          // 3125
    const int edgeGrid = (E + 255) / 256;       // 2500

    // ---- CSR build ----
    hipMemsetAsync(ic, 0, N_NODES * sizeof(int), stream);
    count_deg_kernel<<<edgeGrid, 256, 0, stream>>>(dst, ic, E);
    block_sum_kernel<<<NBLK, 256, 0, stream>>>(ic, bs, N_NODES);
    scan_bs_kernel<<<1, 512, 0, stream>>>(bs, NBLK);
    scan_block_kernel<<<NBLK, 256, 0, stream>>>(ic, bs, pc, N_NODES);
    fill_kernel<<<edgeGrid, 256, 0, stream>>>(src, dst, pc, cs, E);
    // now: start(n) = pc[n] - ic[n], end(n) = pc[n]

    // ---- layer 1: x -> F1 ----
    sage_fused_kernel<<<gemmGrid, 256, 0, stream>>>(x, cs, pc, ic, W1l, W1r, b1, F1, 1);
    // ---- layer 2: F1 -> outTail ----
    sage_fused_kernel<<<gemmGrid, 256, 0, stream>>>(F1, cs, pc, ic, W2l, W2r, b2, outTail, 1);
    // ---- layer 3: outTail -> F1 (h3) ----
    sage_fused_kernel<<<gemmGrid, 256, 0, stream>>>(outTail, cs, pc, ic, W3l, W3r, b3, F1, 0);
    // h3 -> d_out tail
    hipMemcpyAsync(outTail, F1, featBytes, hipMemcpyDeviceToDevice, stream);
    // ---- MLP head: t = relu(h3 @ Wf1 + bf1), in place on F1 ----
    sage_fused_kernel<<<gemmGrid, 256, 0, stream>>>(F1, nullptr, nullptr, nullptr, Wf1, nullptr, bf1, F1, 1);
    // ---- z = t @ Wf2 + bf2, log_softmax -> out head ----
    mlp_softmax_kernel<<<gemmGrid, 256, 0, stream>>>(F1, Wf2, bf2, out);
}

// Round 3
// 870.409 us; speedup vs baseline: 4.4773x; 1.1387x over previous
//
#include <hip/hip_runtime.h>
#include <math.h>

#define N_NODES 100000
#define HDIM    128
#define ODIM    40
#define NBLK    ((N_NODES + 255) / 256)   // 391

// ---------------------------------------------------------------------------
// CSR build: counting sort of edges by dst.
// ---------------------------------------------------------------------------
__global__ __launch_bounds__(256) void count_deg_kernel(
    const int* __restrict__ dst, int* __restrict__ ic, int E)
{
    int e = blockIdx.x * 256 + threadIdx.x;
    if (e < E) atomicAdd(ic + dst[e], 1);
}

__global__ __launch_bounds__(256) void block_sum_kernel(
    const int* __restrict__ ic, int* __restrict__ bs, int n)
{
    __shared__ int sm[256];
    int t = threadIdx.x;
    int i = blockIdx.x * 256 + t;
    sm[t] = (i < n) ? ic[i] : 0;
    __syncthreads();
    for (int s = 128; s > 0; s >>= 1) {
        if (t < s) sm[t] += sm[t + s];
        __syncthreads();
    }
    if (t == 0) bs[blockIdx.x] = sm[0];
}

__global__ __launch_bounds__(512) void scan_bs_kernel(int* __restrict__ bs, int nb)
{
    __shared__ int sm[512];
    int t = threadIdx.x;
    sm[t] = (t < nb) ? bs[t] : 0;
    __syncthreads();
    for (int off = 1; off < 512; off <<= 1) {
        int v = (t >= off) ? sm[t - off] : 0;
        __syncthreads();
        sm[t] += v;
        __syncthreads();
    }
    if (t < nb) bs[t] = (t == 0) ? 0 : sm[t - 1];
}

__global__ __launch_bounds__(256) void scan_block_kernel(
    const int* __restrict__ ic, const int* __restrict__ bs,
    int* __restrict__ pc, int n)
{
    __shared__ int sm[256];
    int t = threadIdx.x;
    int i = blockIdx.x * 256 + t;
    int v = (i < n) ? ic[i] : 0;
    sm[t] = v;
    __syncthreads();
    for (int off = 1; off < 256; off <<= 1) {
        int u = (t >= off) ? sm[t - off] : 0;
        __syncthreads();
        sm[t] += u;
        __syncthreads();
    }
    if (i < n) pc[i] = bs[blockIdx.x] + sm[t] - v;   // exclusive
}

__global__ __launch_bounds__(256) void fill_kernel(
    const int* __restrict__ src, const int* __restrict__ dst,
    int* __restrict__ pc, int* __restrict__ cs, int E)
{
    int e = blockIdx.x * 256 + threadIdx.x;
    if (e < E) {
        int p = atomicAdd(pc + dst[e], 1);
        cs[p] = src[e];
    }
}
// after fill: end(n) = pc[n], start(n) = pc[n] - ic[n]

// ---------------------------------------------------------------------------
// Mean-gather, one wave per node. Neighbor indices are loaded 64-at-a-time
// with ONE coalesced load + shfl broadcast, so the deg feature gathers are
// independent loads all in flight (no per-edge dependent chain).
// A[node] = mean(feat[neighbors(node)]), pre-scaled by 1/deg.
// ---------------------------------------------------------------------------
__global__ __launch_bounds__(256) void gather_mean_kernel(
    const float* __restrict__ feat,
    const int* __restrict__ cs, const int* __restrict__ pc, const int* __restrict__ ic,
    float* __restrict__ A)
{
    const int wave = threadIdx.x >> 6;          // 0..3
    const int lane = threadIdx.x & 63;
    const int node = blockIdx.x * 4 + wave;     // grid = 25000 -> exact
    const int end  = pc[node];
    const int deg  = ic[node];
    const int start = end - deg;

    float2 acc = {0.f, 0.f};
    for (int b = start; b < end; b += 64) {
        int m = end - b; if (m > 64) m = 64;
        int idx = cs[b + (lane < m ? lane : 0)];
        for (int j = 0; j < m; ++j) {
            int s = __shfl(idx, j, 64);
            float2 v = *reinterpret_cast<const float2*>(feat + (size_t)s * HDIM + lane * 2);
            acc.x += v.x; acc.y += v.y;
        }
    }
    float inv = 1.0f / (float)(deg > 0 ? deg : 1);
    float2 r; r.x = acc.x * inv; r.y = acc.y * inv;
    *reinterpret_cast<float2*>(A + (size_t)node * HDIM + lane * 2) = r;
}

// ---------------------------------------------------------------------------
// Dual GEMM: out = [relu]( Ain @ Wl + bias [+ Bin @ Wr] )
// Bin/Wr == nullptr -> plain linear. Safe for out == Bin (rows staged to LDS
// with a barrier before any write; each block writes only its own 32 rows).
// Block: 256 threads, 32 rows x 128 cols; thread computes 4x4.
// ---------------------------------------------------------------------------
#define FMA4(A_, s_, W_) { (A_).x += (s_) * (W_).x; (A_).y += (s_) * (W_).y; \
                           (A_).z += (s_) * (W_).z; (A_).w += (s_) * (W_).w; }

__global__ __launch_bounds__(256) void sage_gemm_kernel(
    const float* __restrict__ Ain, const float* __restrict__ Bin,
    const float* __restrict__ Wl, const float* __restrict__ Wr,
    const float* __restrict__ bias, float* __restrict__ out, int do_relu)
{
    __shared__ float sA[32][HDIM];
    __shared__ float sB[32][HDIM];
    const int tid  = threadIdx.x;
    const int base = blockIdx.x * 32;
    const bool haveB = (Bin != nullptr);

    for (int it = 0; it < 4; ++it) {
        int f   = it * 256 + tid;
        int row = f >> 5;
        int cc  = (f & 31) << 2;
        *reinterpret_cast<float4*>(&sA[row][cc]) =
            *reinterpret_cast<const float4*>(Ain + (size_t)(base + row) * HDIM + cc);
        if (haveB) {
            *reinterpret_cast<float4*>(&sB[row][cc]) =
                *reinterpret_cast<const float4*>(Bin + (size_t)(base + row) * HDIM + cc);
        }
    }
    __syncthreads();

    const int jg   = tid & 31;
    const int rg   = tid >> 5;
    const int col0 = jg << 2;
    const int row0 = rg << 2;

    float4 acc0 = {0.f,0.f,0.f,0.f}, acc1 = {0.f,0.f,0.f,0.f};
    float4 acc2 = {0.f,0.f,0.f,0.f}, acc3 = {0.f,0.f,0.f,0.f};

    for (int k = 0; k < HDIM; k += 4) {
        float4 w0 = *reinterpret_cast<const float4*>(Wl + (size_t)(k + 0) * HDIM + col0);
        float4 w1 = *reinterpret_cast<const float4*>(Wl + (size_t)(k + 1) * HDIM + col0);
        float4 w2 = *reinterpret_cast<const float4*>(Wl + (size_t)(k + 2) * HDIM + col0);
        float4 w3 = *reinterpret_cast<const float4*>(Wl + (size_t)(k + 3) * HDIM + col0);
        float4 a0 = *reinterpret_cast<const float4*>(&sA[row0 + 0][k]);
        float4 a1 = *reinterpret_cast<const float4*>(&sA[row0 + 1][k]);
        float4 a2 = *reinterpret_cast<const float4*>(&sA[row0 + 2][k]);
        float4 a3 = *reinterpret_cast<const float4*>(&sA[row0 + 3][k]);
        FMA4(acc0, a0.x, w0) FMA4(acc0, a0.y, w1) FMA4(acc0, a0.z, w2) FMA4(acc0, a0.w, w3)
        FMA4(acc1, a1.x, w0) FMA4(acc1, a1.y, w1) FMA4(acc1, a1.z, w2) FMA4(acc1, a1.w, w3)
        FMA4(acc2, a2.x, w0) FMA4(acc2, a2.y, w1) FMA4(acc2, a2.z, w2) FMA4(acc2, a2.w, w3)
        FMA4(acc3, a3.x, w0) FMA4(acc3, a3.y, w1) FMA4(acc3, a3.z, w2) FMA4(acc3, a3.w, w3)
    }

    if (Wr != nullptr) {
        for (int k = 0; k < HDIM; k += 4) {
            float4 w0 = *reinterpret_cast<const float4*>(Wr + (size_t)(k + 0) * HDIM + col0);
            float4 w1 = *reinterpret_cast<const float4*>(Wr + (size_t)(k + 1) * HDIM + col0);
            float4 w2 = *reinterpret_cast<const float4*>(Wr + (size_t)(k + 2) * HDIM + col0);
            float4 w3 = *reinterpret_cast<const float4*>(Wr + (size_t)(k + 3) * HDIM + col0);
            float4 a0 = *reinterpret_cast<const float4*>(&sB[row0 + 0][k]);
            float4 a1 = *reinterpret_cast<const float4*>(&sB[row0 + 1][k]);
            float4 a2 = *reinterpret_cast<const float4*>(&sB[row0 + 2][k]);
            float4 a3 = *reinterpret_cast<const float4*>(&sB[row0 + 3][k]);
            FMA4(acc0, a0.x, w0) FMA4(acc0, a0.y, w1) FMA4(acc0, a0.z, w2) FMA4(acc0, a0.w, w3)
            FMA4(acc1, a1.x, w0) FMA4(acc1, a1.y, w1) FMA4(acc1, a1.z, w2) FMA4(acc1, a1.w, w3)
            FMA4(acc2, a2.x, w0) FMA4(acc2, a2.y, w1) FMA4(acc2, a2.z, w2) FMA4(acc2, a2.w, w3)
            FMA4(acc3, a3.x, w0) FMA4(acc3, a3.y, w1) FMA4(acc3, a3.z, w2) FMA4(acc3, a3.w, w3)
        }
    }

    float4 bv = *reinterpret_cast<const float4*>(bias + col0);
    acc0.x += bv.x; acc0.y += bv.y; acc0.z += bv.z; acc0.w += bv.w;
    acc1.x += bv.x; acc1.y += bv.y; acc1.z += bv.z; acc1.w += bv.w;
    acc2.x += bv.x; acc2.y += bv.y; acc2.z += bv.z; acc2.w += bv.w;
    acc3.x += bv.x; acc3.y += bv.y; acc3.z += bv.z; acc3.w += bv.w;

    if (do_relu) {
        acc0.x = fmaxf(acc0.x, 0.f); acc0.y = fmaxf(acc0.y, 0.f); acc0.z = fmaxf(acc0.z, 0.f); acc0.w = fmaxf(acc0.w, 0.f);
        acc1.x = fmaxf(acc1.x, 0.f); acc1.y = fmaxf(acc1.y, 0.f); acc1.z = fmaxf(acc1.z, 0.f); acc1.w = fmaxf(acc1.w, 0.f);
        acc2.x = fmaxf(acc2.x, 0.f); acc2.y = fmaxf(acc2.y, 0.f); acc2.z = fmaxf(acc2.z, 0.f); acc2.w = fmaxf(acc2.w, 0.f);
        acc3.x = fmaxf(acc3.x, 0.f); acc3.y = fmaxf(acc3.y, 0.f); acc3.z = fmaxf(acc3.z, 0.f); acc3.w = fmaxf(acc3.w, 0.f);
    }

    *reinterpret_cast<float4*>(out + (size_t)(base + row0 + 0) * HDIM + col0) = acc0;
    *reinterpret_cast<float4*>(out + (size_t)(base + row0 + 1) * HDIM + col0) = acc1;
    *reinterpret_cast<float4*>(out + (size_t)(base + row0 + 2) * HDIM + col0) = acc2;
    *reinterpret_cast<float4*>(out + (size_t)(base + row0 + 3) * HDIM + col0) = acc3;
}

// ---------------------------------------------------------------------------
// Final: z = t @ Wf2 + bf2  (128 -> 40), then row-wise log_softmax.
// ---------------------------------------------------------------------------
__global__ __launch_bounds__(256) void mlp_softmax_kernel(
    const float* __restrict__ t, const float* __restrict__ Wf2,
    const float* __restrict__ bf2, float* __restrict__ out)
{
    __shared__ float sT[32][HDIM];
    __shared__ float sW[HDIM * ODIM];
    __shared__ float sb[ODIM];
    __shared__ float sZ[32][ODIM];

    const int tid  = threadIdx.x;
    const int base = blockIdx.x * 32;

    for (int i = tid; i < HDIM * ODIM; i += 256) sW[i] = Wf2[i];
    if (tid < ODIM) sb[tid] = bf2[tid];
    for (int it = 0; it < 4; ++it) {
        int f   = it * 256 + tid;
        int row = f >> 5;
        int cc  = (f & 31) << 2;
        *reinterpret_cast<float4*>(&sT[row][cc]) =
            *reinterpret_cast<const float4*>(t + (size_t)(base + row) * HDIM + cc);
    }
    __syncthreads();

    for (int it = 0; it < 5; ++it) {
        int idx = it * 256 + tid;
        int n = idx / ODIM;
        int o = idx - n * ODIM;
        float s = sb[o];
        #pragma unroll 8
        for (int k = 0; k < HDIM; ++k) s += sT[n][k] * sW[k * ODIM + o];
        sZ[n][o] = s;
    }
    __syncthreads();

    if (tid < 32) {
        float m = -INFINITY;
        #pragma unroll
        for (int o = 0; o < ODIM; ++o) m = fmaxf(m, sZ[tid][o]);
        float sum = 0.f;
        #pragma unroll
        for (int o = 0; o < ODIM; ++o) sum += expf(sZ[tid][o] - m);
        float lse = logf(sum) + m;
        size_t off = (size_t)(base + tid) * ODIM;
        #pragma unroll
        for (int o = 0; o < ODIM; ++o) out[off + o] = sZ[tid][o] - lse;
    }
}

// ---------------------------------------------------------------------------
extern "C" void kernel_launch(void* const* d_in, const int* in_sizes, int n_in,
                              void* d_out, int out_size, void* d_ws, size_t ws_size,
                              hipStream_t stream) {
    const float* x   = (const float*)d_in[0];
    const int*   ei  = (const int*)d_in[1];
    const int E = in_sizes[1] / 2;
    const int* src = ei;
    const int* dst = ei + E;

    const float* W1l = (const float*)d_in[2];
    const float* b1  = (const float*)d_in[3];
    const float* W1r = (const float*)d_in[4];
    const float* W2l = (const float*)d_in[5];
    const float* b2  = (const float*)d_in[6];
    const float* W2r = (const float*)d_in[7];
    const float* W3l = (const float*)d_in[8];
    const float* b3  = (const float*)d_in[9];
    const float* W3r = (const float*)d_in[10];
    const float* Wf1 = (const float*)d_in[11];
    const float* bf1 = (const float*)d_in[12];
    const float* Wf2 = (const float*)d_in[13];
    const float* bf2 = (const float*)d_in[14];

    float* out     = (float*)d_out;
    float* outTail = out + (size_t)N_NODES * ODIM;   // tuple part 2: h [N,128]

    // CSR arrays live in the d_out HEAD region (16 MB; only written by the
    // final softmax, after the last CSR use). Rebuilt every launch.
    int* ic = (int*)out;            // 100352 ints
    int* pc = ic + 100352;          // 100352 ints
    int* bs = pc + 100352;          // 1024 ints
    int* cs = bs + 1024;            // E ints   (total ~3.4 MB < 16 MB)

    // Workspace: A (aggregate) | F1 (features)  = 102.4 MB
    float* A  = (float*)d_ws;
    float* F1 = A + (size_t)N_NODES * HDIM;

    const int gemmGrid   = N_NODES / 32;     // 3125
    const int gatherGrid = N_NODES / 4;      // 25000
    const int edgeGrid   = (E + 255) / 256;  // 2500

    // ---- CSR build ----
    hipMemsetAsync(ic, 0, N_NODES * sizeof(int), stream);
    count_deg_kernel<<<edgeGrid, 256, 0, stream>>>(dst, ic, E);
    block_sum_kernel<<<NBLK, 256, 0, stream>>>(ic, bs, N_NODES);
    scan_bs_kernel<<<1, 512, 0, stream>>>(bs, NBLK);
    scan_block_kernel<<<NBLK, 256, 0, stream>>>(ic, bs, pc, N_NODES);
    fill_kernel<<<edgeGrid, 256, 0, stream>>>(src, dst, pc, cs, E);

    // ---- layer 1: x -> F1 ----
    gather_mean_kernel<<<gatherGrid, 256, 0, stream>>>(x, cs, pc, ic, A);
    sage_gemm_kernel<<<gemmGrid, 256, 0, stream>>>(A, x, W1l, W1r, b1, F1, 1);

    // ---- layer 2: F1 -> outTail ----
    gather_mean_kernel<<<gatherGrid, 256, 0, stream>>>(F1, cs, pc, ic, A);
    sage_gemm_kernel<<<gemmGrid, 256, 0, stream>>>(A, F1, W2l, W2r, b2, outTail, 1);

    // ---- layer 3: outTail -> outTail (in place; h3 lands in d_out tail) ----
    gather_mean_kernel<<<gatherGrid, 256, 0, stream>>>(outTail, cs, pc, ic, A);
    sage_gemm_kernel<<<gemmGrid, 256, 0, stream>>>(A, outTail, W3l, W3r, b3, outTail, 0);

    // ---- MLP head: t = relu(h3 @ Wf1 + bf1) -> F1 ----
    sage_gemm_kernel<<<gemmGrid, 256, 0, stream>>>(outTail, nullptr, Wf1, nullptr, bf1, F1, 1);
    // ---- z = t @ Wf2 + bf2, log_softmax -> out head (overwrites CSR debris) ----
    mlp_softmax_kernel<<<gemmGrid, 256, 0, stream>>>(F1, Wf2, bf2, out);
}

// Round 4
// 587.278 us; speedup vs baseline: 6.6358x; 1.4821x over previous
//
#include <hip/hip_runtime.h>
#include <math.h>

#define N_NODES 100000
#define HDIM    128
#define ODIM    40
#define NBLK    ((N_NODES + 255) / 256)   // 391

typedef unsigned short u16;
typedef unsigned int   u32;
typedef short bf16x8 __attribute__((ext_vector_type(8)));   // 8 bf16 in 4 VGPRs
typedef float f32x4  __attribute__((ext_vector_type(4)));

// ---------------- bf16 helpers ----------------
__device__ inline float bf16lo_to_f(u32 v) {
    u32 u = v << 16; float f; __builtin_memcpy(&f, &u, 4); return f;
}
__device__ inline float bf16hi_to_f(u32 v) {
    u32 u = v & 0xffff0000u; float f; __builtin_memcpy(&f, &u, 4); return f;
}
__device__ inline u16 f_to_bf16(float f) {
    u32 u; __builtin_memcpy(&u, &f, 4);
    u32 r = (u + 0x7fffu + ((u >> 16) & 1u)) >> 16;   // round-nearest-even
    return (u16)r;
}
__device__ inline u32 pack_bf16x2(float a, float b) {
    return (u32)f_to_bf16(a) | ((u32)f_to_bf16(b) << 16);
}

// ---------------------------------------------------------------------------
// CSR build (counting sort by dst) — unchanged from round 3.
// ---------------------------------------------------------------------------
__global__ __launch_bounds__(256) void count_deg_kernel(
    const int* __restrict__ dst, int* __restrict__ ic, int E)
{
    int e = blockIdx.x * 256 + threadIdx.x;
    if (e < E) atomicAdd(ic + dst[e], 1);
}

__global__ __launch_bounds__(256) void block_sum_kernel(
    const int* __restrict__ ic, int* __restrict__ bs, int n)
{
    __shared__ int sm[256];
    int t = threadIdx.x;
    int i = blockIdx.x * 256 + t;
    sm[t] = (i < n) ? ic[i] : 0;
    __syncthreads();
    for (int s = 128; s > 0; s >>= 1) {
        if (t < s) sm[t] += sm[t + s];
        __syncthreads();
    }
    if (t == 0) bs[blockIdx.x] = sm[0];
}

__global__ __launch_bounds__(512) void scan_bs_kernel(int* __restrict__ bs, int nb)
{
    __shared__ int sm[512];
    int t = threadIdx.x;
    sm[t] = (t < nb) ? bs[t] : 0;
    __syncthreads();
    for (int off = 1; off < 512; off <<= 1) {
        int v = (t >= off) ? sm[t - off] : 0;
        __syncthreads();
        sm[t] += v;
        __syncthreads();
    }
    if (t < nb) bs[t] = (t == 0) ? 0 : sm[t - 1];
}

__global__ __launch_bounds__(256) void scan_block_kernel(
    const int* __restrict__ ic, const int* __restrict__ bs,
    int* __restrict__ pc, int n)
{
    __shared__ int sm[256];
    int t = threadIdx.x;
    int i = blockIdx.x * 256 + t;
    int v = (i < n) ? ic[i] : 0;
    sm[t] = v;
    __syncthreads();
    for (int off = 1; off < 256; off <<= 1) {
        int u = (t >= off) ? sm[t - off] : 0;
        __syncthreads();
        sm[t] += u;
        __syncthreads();
    }
    if (i < n) pc[i] = bs[blockIdx.x] + sm[t] - v;   // exclusive
}

__global__ __launch_bounds__(256) void fill_kernel(
    const int* __restrict__ src, const int* __restrict__ dst,
    int* __restrict__ pc, int* __restrict__ cs, int E)
{
    int e = blockIdx.x * 256 + threadIdx.x;
    if (e < E) {
        int p = atomicAdd(pc + dst[e], 1);
        cs[p] = src[e];
    }
}
// after fill: end(n) = pc[n], start(n) = pc[n] - ic[n]

// ---------------------------------------------------------------------------
// fp32 -> bf16 feature conversion (2 elements / thread).
// ---------------------------------------------------------------------------
__global__ __launch_bounds__(256) void f2bf_kernel(
    const float2* __restrict__ in, u32* __restrict__ out, int n2)
{
    int i = blockIdx.x * 256 + threadIdx.x;
    if (i < n2) { float2 v = in[i]; out[i] = pack_bf16x2(v.x, v.y); }
}

// ---------------------------------------------------------------------------
// Pack 128x128 fp32 weight matrices into bf16 MFMA B-fragment order:
//   frag for (ntile, kslice): 64 lanes x 8 bf16, lane = q*16 + (n&15),
//   element j: B[k = kslice*32 + q*8 + j][n = ntile*16 + (n&15)]
// ---------------------------------------------------------------------------
struct WPtrs { const float* w[7]; };

__global__ __launch_bounds__(256) void pack_w_kernel(WPtrs p, u16* __restrict__ out)
{
    int mat = blockIdx.y;
    int e = blockIdx.x * 256 + threadIdx.x;      // 0..16383
    int k = e >> 7, n = e & 127;
    float v = p.w[mat][e];
    int nt = n >> 4, ks = k >> 5, q = (k >> 3) & 3, j = k & 7;
    int dst = mat * 16384 + (((nt * 4 + ks) * 64 + q * 16 + (n & 15)) << 3) + j;
    out[dst] = f_to_bf16(v);
}

// ---------------------------------------------------------------------------
// Mean-gather on bf16 features, one wave per node. Coalesced index load +
// shfl broadcast; lane handles 2 columns (one u32 = 2 bf16), fp32 accumulate.
// ---------------------------------------------------------------------------
__global__ __launch_bounds__(256) void gather_mean16_kernel(
    const u32* __restrict__ feat,    // [N][64] u32 (=128 bf16)
    const int* __restrict__ cs, const int* __restrict__ pc, const int* __restrict__ ic,
    u32* __restrict__ A)             // [N][64] u32
{
    const int wave = threadIdx.x >> 6;
    const int lane = threadIdx.x & 63;
    const int node = blockIdx.x * 4 + wave;
    const int end  = pc[node];
    const int deg  = ic[node];
    const int start = end - deg;

    float ax = 0.f, ay = 0.f;
    for (int b = start; b < end; b += 64) {
        int m = end - b; if (m > 64) m = 64;
        int idx = cs[b + (lane < m ? lane : 0)];
        for (int j = 0; j < m; ++j) {
            int s = __shfl(idx, j, 64);
            u32 v = feat[((size_t)s << 6) + lane];
            ax += bf16lo_to_f(v);
            ay += bf16hi_to_f(v);
        }
    }
    float inv = 1.0f / (float)(deg > 0 ? deg : 1);
    A[((size_t)node << 6) + lane] = pack_bf16x2(ax * inv, ay * inv);
}

// ---------------------------------------------------------------------------
// MFMA dual GEMM: out = [relu]( A1 @ W1 + bias [+ A2 @ W2] )
//   A1/A2: bf16 [N][128]; W1p/W2p: packed bf16 frag-order; bias fp32.
//   out16 (bf16) and/or out32 (fp32) outputs, either may be null.
// Block: 256 thr (4 waves), tile 64 rows x 128 cols. Wave w: rows w*16..+15,
// all 8 n-tiles; 16x16x32 MFMA, fp32 acc. A staged in LDS in A-frag order
// (linear conflict-free ds_read_b128); W-frags streamed from L1/L2.
// ---------------------------------------------------------------------------
__global__ __launch_bounds__(256) void mfma_gemm_kernel(
    const u16* __restrict__ A1, const u16* __restrict__ A2,
    const u16* __restrict__ W1p, const u16* __restrict__ W2p,
    const float* __restrict__ bias,
    u16* __restrict__ out16, float* __restrict__ out32, int do_relu)
{
    __shared__ u16 sAll[2 * 8192];    // 2 x 64x128 bf16 = 32 KB, frag order
    const int tid  = threadIdx.x;
    const int base = blockIdx.x * 64;
    const int nmats = (A2 != nullptr) ? 2 : 1;

    // ---- stage A-tiles into LDS, A-frag order ----
    // chunk c: row = c>>4 (0..63), ch8 = c&15 (16B chunk in row)
    // dest chunk = ((row>>4)*4 + ks)*64 + q*16 + (row&15),  q=ch8&3, ks=ch8>>2
    for (int mat = 0; mat < nmats; ++mat) {
        const u16* Ain = mat ? A2 : A1;
        u16* sDst = &sAll[mat * 8192];
        for (int it = 0; it < 4; ++it) {
            int c   = it * 256 + tid;
            int row = c >> 4;
            int ch8 = c & 15;
            int rowg = base + row; if (rowg > N_NODES - 1) rowg = N_NODES - 1;
            uint4 v = *reinterpret_cast<const uint4*>(Ain + ((size_t)rowg << 7) + (ch8 << 3));
            int q = ch8 & 3, ks = ch8 >> 2;
            int dc = ((row >> 4) * 4 + ks) * 64 + q * 16 + (row & 15);
            *reinterpret_cast<uint4*>(sDst + (dc << 3)) = v;
        }
    }
    __syncthreads();

    const int wave = tid >> 6;
    const int lane = tid & 63;

    f32x4 acc[8];
    #pragma unroll
    for (int nt = 0; nt < 8; ++nt) acc[nt] = (f32x4){0.f, 0.f, 0.f, 0.f};

    for (int mat = 0; mat < nmats; ++mat) {
        const u16* Wp = mat ? W2p : W1p;
        const u16* sA = &sAll[mat * 8192];
        #pragma unroll
        for (int ks = 0; ks < 4; ++ks) {
            bf16x8 a = *reinterpret_cast<const bf16x8*>(sA + (((wave * 4 + ks) * 64 + lane) << 3));
            #pragma unroll
            for (int nt = 0; nt < 8; ++nt) {
                bf16x8 b = *reinterpret_cast<const bf16x8*>(Wp + (((nt * 4 + ks) * 64 + lane) << 3));
                acc[nt] = __builtin_amdgcn_mfma_f32_16x16x32_bf16(a, b, acc[nt], 0, 0, 0);
            }
        }
    }

    // ---- epilogue: D[row = q*4+r][col = m] per 16x16 tile ----
    const int m = lane & 15;
    const int q = lane >> 4;
    #pragma unroll
    for (int nt = 0; nt < 8; ++nt) {
        int col = nt * 16 + m;
        float bv = bias[col];
        #pragma unroll
        for (int r = 0; r < 4; ++r) {
            int rowg = base + wave * 16 + q * 4 + r;
            if (rowg >= N_NODES) continue;
            float v = acc[nt][r] + bv;
            if (do_relu) v = fmaxf(v, 0.f);
            if (out16) out16[((size_t)rowg << 7) + col] = f_to_bf16(v);
            if (out32) out32[((size_t)rowg << 7) + col] = v;
        }
    }
}

// ---------------------------------------------------------------------------
// Final: z = t @ Wf2 + bf2  (128 -> 40, t in bf16), then row-wise log_softmax.
// ---------------------------------------------------------------------------
__global__ __launch_bounds__(256) void mlp_softmax_kernel(
    const u32* __restrict__ t,       // bf16 [N][128] as [N][64] u32
    const float* __restrict__ Wf2, const float* __restrict__ bf2,
    float* __restrict__ out)
{
    __shared__ float sT[32][HDIM];
    __shared__ float sW[HDIM * ODIM];
    __shared__ float sb[ODIM];
    __shared__ float sZ[32][ODIM];

    const int tid  = threadIdx.x;
    const int base = blockIdx.x * 32;

    for (int i = tid; i < HDIM * ODIM; i += 256) sW[i] = Wf2[i];
    if (tid < ODIM) sb[tid] = bf2[tid];
    for (int it = 0; it < 8; ++it) {
        int f   = it * 256 + tid;          // u32 index among 32*64
        int row = f >> 6;
        int cu  = f & 63;
        u32 v = t[((size_t)(base + row) << 6) + cu];
        sT[row][cu * 2]     = bf16lo_to_f(v);
        sT[row][cu * 2 + 1] = bf16hi_to_f(v);
    }
    __syncthreads();

    for (int it = 0; it < 5; ++it) {
        int idx = it * 256 + tid;
        int n = idx / ODIM;
        int o = idx - n * ODIM;
        float s = sb[o];
        #pragma unroll 8
        for (int k = 0; k < HDIM; ++k) s += sT[n][k] * sW[k * ODIM + o];
        sZ[n][o] = s;
    }
    __syncthreads();

    if (tid < 32) {
        float mx = -INFINITY;
        #pragma unroll
        for (int o = 0; o < ODIM; ++o) mx = fmaxf(mx, sZ[tid][o]);
        float sum = 0.f;
        #pragma unroll
        for (int o = 0; o < ODIM; ++o) sum += expf(sZ[tid][o] - mx);
        float lse = logf(sum) + mx;
        size_t off = (size_t)(base + tid) * ODIM;
        #pragma unroll
        for (int o = 0; o < ODIM; ++o) out[off + o] = sZ[tid][o] - lse;
    }
}

// ---------------------------------------------------------------------------
extern "C" void kernel_launch(void* const* d_in, const int* in_sizes, int n_in,
                              void* d_out, int out_size, void* d_ws, size_t ws_size,
                              hipStream_t stream) {
    const float* x   = (const float*)d_in[0];
    const int*   ei  = (const int*)d_in[1];
    const int E = in_sizes[1] / 2;
    const int* src = ei;
    const int* dst = ei + E;

    const float* W1l = (const float*)d_in[2];
    const float* b1  = (const float*)d_in[3];
    const float* W1r = (const float*)d_in[4];
    const float* W2l = (const float*)d_in[5];
    const float* b2  = (const float*)d_in[6];
    const float* W2r = (const float*)d_in[7];
    const float* W3l = (const float*)d_in[8];
    const float* b3  = (const float*)d_in[9];
    const float* W3r = (const float*)d_in[10];
    const float* Wf1 = (const float*)d_in[11];
    const float* bf1 = (const float*)d_in[12];
    const float* Wf2 = (const float*)d_in[13];
    const float* bf2 = (const float*)d_in[14];

    float* out     = (float*)d_out;
    float* outTail = out + (size_t)N_NODES * ODIM;   // tuple part 2: h [N,128] fp32

    // CSR arrays live in d_out HEAD (16 MB; overwritten by final softmax).
    int* ic = (int*)out;            // 100352 ints
    int* pc = ic + 100352;          // 100352 ints
    int* bs = pc + 100352;          // 1024 ints
    int* cs = bs + 1024;            // E ints  (total ~3.4 MB)

    // Workspace (u16 units): X16 | F16a | F16b | A16 | Wpk(7x16384)
    const size_t FEAT16 = (size_t)N_NODES * HDIM;   // 12.8M u16 = 25.6 MB
    u16* X16  = (u16*)d_ws;
    u16* F16a = X16  + FEAT16;
    u16* F16b = F16a + FEAT16;
    u16* A16  = F16b + FEAT16;
    u16* Wpk  = A16  + FEAT16;                      // 7*16384 u16 = 229 KB
    u16* Wp_1l = Wpk + 0 * 16384;
    u16* Wp_1r = Wpk + 1 * 16384;
    u16* Wp_2l = Wpk + 2 * 16384;
    u16* Wp_2r = Wpk + 3 * 16384;
    u16* Wp_3l = Wpk + 4 * 16384;
    u16* Wp_3r = Wpk + 5 * 16384;
    u16* Wp_f1 = Wpk + 6 * 16384;

    const int gemmGrid   = (N_NODES + 63) / 64;   // 1563
    const int smaxGrid   = N_NODES / 32;          // 3125
    const int gatherGrid = N_NODES / 4;           // 25000
    const int edgeGrid   = (E + 255) / 256;       // 2500
    const int cvtGrid    = (N_NODES * HDIM / 2 + 255) / 256;  // 25000

    // ---- CSR build ----
    hipMemsetAsync(ic, 0, N_NODES * sizeof(int), stream);
    count_deg_kernel<<<edgeGrid, 256, 0, stream>>>(dst, ic, E);
    block_sum_kernel<<<NBLK, 256, 0, stream>>>(ic, bs, N_NODES);
    scan_bs_kernel<<<1, 512, 0, stream>>>(bs, NBLK);
    scan_block_kernel<<<NBLK, 256, 0, stream>>>(ic, bs, pc, N_NODES);
    fill_kernel<<<edgeGrid, 256, 0, stream>>>(src, dst, pc, cs, E);

    // ---- prep: x -> bf16, pack weights ----
    f2bf_kernel<<<cvtGrid, 256, 0, stream>>>((const float2*)x, (u32*)X16, N_NODES * HDIM / 2);
    WPtrs wp; wp.w[0] = W1l; wp.w[1] = W1r; wp.w[2] = W2l; wp.w[3] = W2r;
    wp.w[4] = W3l; wp.w[5] = W3r; wp.w[6] = Wf1;
    pack_w_kernel<<<dim3(64, 7), 256, 0, stream>>>(wp, Wpk);

    // ---- layer 1: X16 -> F16a ----
    gather_mean16_kernel<<<gatherGrid, 256, 0, stream>>>((const u32*)X16, cs, pc, ic, (u32*)A16);
    mfma_gemm_kernel<<<gemmGrid, 256, 0, stream>>>(A16, X16, Wp_1l, Wp_1r, b1, F16a, nullptr, 1);

    // ---- layer 2: F16a -> F16b ----
    gather_mean16_kernel<<<gatherGrid, 256, 0, stream>>>((const u32*)F16a, cs, pc, ic, (u32*)A16);
    mfma_gemm_kernel<<<gemmGrid, 256, 0, stream>>>(A16, F16a, Wp_2l, Wp_2r, b2, F16b, nullptr, 1);

    // ---- layer 3: F16b -> F16a (bf16) + outTail (fp32 h3), no relu ----
    gather_mean16_kernel<<<gatherGrid, 256, 0, stream>>>((const u32*)F16b, cs, pc, ic, (u32*)A16);
    mfma_gemm_kernel<<<gemmGrid, 256, 0, stream>>>(A16, F16b, Wp_3l, Wp_3r, b3, F16a, outTail, 0);

    // ---- MLP head: t = relu(h3 @ Wf1 + bf1) -> A16 (bf16) ----
    mfma_gemm_kernel<<<gemmGrid, 256, 0, stream>>>(F16a, nullptr, Wp_f1, nullptr, bf1, A16, nullptr, 1);

    // ---- z = t @ Wf2 + bf2, log_softmax -> out head (overwrites CSR debris) ----
    mlp_softmax_kernel<<<smaxGrid, 256, 0, stream>>>((const u32*)A16, Wf2, bf2, out);
}

// Round 5
// 522.383 us; speedup vs baseline: 7.4601x; 1.1242x over previous
//
#include <hip/hip_runtime.h>
#include <math.h>

#define N_NODES 100000
#define HDIM    128
#define ODIM    40
#define NBLK    ((N_NODES + 255) / 256)   // 391

typedef unsigned short u16;
typedef unsigned int   u32;
typedef short bf16x8 __attribute__((ext_vector_type(8)));   // 8 bf16 in 4 VGPRs
typedef float f32x4  __attribute__((ext_vector_type(4)));

// ---------------- bf16 helpers ----------------
__device__ inline float bf16lo_to_f(u32 v) {
    u32 u = v << 16; float f; __builtin_memcpy(&f, &u, 4); return f;
}
__device__ inline float bf16hi_to_f(u32 v) {
    u32 u = v & 0xffff0000u; float f; __builtin_memcpy(&f, &u, 4); return f;
}
__device__ inline u16 f_to_bf16(float f) {
    u32 u; __builtin_memcpy(&u, &f, 4);
    u32 r = (u + 0x7fffu + ((u >> 16) & 1u)) >> 16;   // round-nearest-even
    return (u16)r;
}
__device__ inline u32 pack_bf16x2(float a, float b) {
    return (u32)f_to_bf16(a) | ((u32)f_to_bf16(b) << 16);
}

// ---------------------------------------------------------------------------
// CSR build (counting sort by dst).
// ---------------------------------------------------------------------------
__global__ __launch_bounds__(256) void count_deg_kernel(
    const int* __restrict__ dst, int* __restrict__ ic, int E)
{
    int e = blockIdx.x * 256 + threadIdx.x;
    if (e < E) atomicAdd(ic + dst[e], 1);
}

__global__ __launch_bounds__(256) void block_sum_kernel(
    const int* __restrict__ ic, int* __restrict__ bs, int n)
{
    __shared__ int sm[256];
    int t = threadIdx.x;
    int i = blockIdx.x * 256 + t;
    sm[t] = (i < n) ? ic[i] : 0;
    __syncthreads();
    for (int s = 128; s > 0; s >>= 1) {
        if (t < s) sm[t] += sm[t + s];
        __syncthreads();
    }
    if (t == 0) bs[blockIdx.x] = sm[0];
}

__global__ __launch_bounds__(512) void scan_bs_kernel(int* __restrict__ bs, int nb)
{
    __shared__ int sm[512];
    int t = threadIdx.x;
    sm[t] = (t < nb) ? bs[t] : 0;
    __syncthreads();
    for (int off = 1; off < 512; off <<= 1) {
        int v = (t >= off) ? sm[t - off] : 0;
        __syncthreads();
        sm[t] += v;
        __syncthreads();
    }
    if (t < nb) bs[t] = (t == 0) ? 0 : sm[t - 1];
}

__global__ __launch_bounds__(256) void scan_block_kernel(
    const int* __restrict__ ic, const int* __restrict__ bs,
    int* __restrict__ pc, int n)
{
    __shared__ int sm[256];
    int t = threadIdx.x;
    int i = blockIdx.x * 256 + t;
    int v = (i < n) ? ic[i] : 0;
    sm[t] = v;
    __syncthreads();
    for (int off = 1; off < 256; off <<= 1) {
        int u = (t >= off) ? sm[t - off] : 0;
        __syncthreads();
        sm[t] += u;
        __syncthreads();
    }
    if (i < n) pc[i] = bs[blockIdx.x] + sm[t] - v;   // exclusive
}

__global__ __launch_bounds__(256) void fill_kernel(
    const int* __restrict__ src, const int* __restrict__ dst,
    int* __restrict__ pc, int* __restrict__ cs, int E)
{
    int e = blockIdx.x * 256 + threadIdx.x;
    if (e < E) {
        int p = atomicAdd(pc + dst[e], 1);
        cs[p] = src[e];
    }
}
// after fill: end(n) = pc[n], start(n) = pc[n] - ic[n]

// ---------------------------------------------------------------------------
// fp32 -> bf16 feature conversion (2 elements / thread).
// ---------------------------------------------------------------------------
__global__ __launch_bounds__(256) void f2bf_kernel(
    const float2* __restrict__ in, u32* __restrict__ out, int n2)
{
    int i = blockIdx.x * 256 + threadIdx.x;
    if (i < n2) { float2 v = in[i]; out[i] = pack_bf16x2(v.x, v.y); }
}

// ---------------------------------------------------------------------------
// Pack 128x128 fp32 weight matrices into bf16 MFMA B-fragment order:
//   frag (ntile, kslice): 64 lanes x 8 bf16, lane = q*16 + (n&15),
//   element j: B[k = kslice*32 + q*8 + j][n = ntile*16 + (n&15)]
// ---------------------------------------------------------------------------
struct WPtrs { const float* w[7]; };

__global__ __launch_bounds__(256) void pack_w_kernel(WPtrs p, u16* __restrict__ out)
{
    int mat = blockIdx.y;
    int e = blockIdx.x * 256 + threadIdx.x;      // 0..16383
    int k = e >> 7, n = e & 127;
    float v = p.w[mat][e];
    int nt = n >> 4, ks = k >> 5, q = (k >> 3) & 3, j = k & 7;
    int dst = mat * 16384 + (((nt * 4 + ks) * 64 + q * 16 + (n & 15)) << 3) + j;
    out[dst] = f_to_bf16(v);
}

// Pack Wf2 [128][40] into 128x48 (zero-padded) B-frag order: 3 ntiles x 4 ks.
__global__ __launch_bounds__(256) void pack_wf2_kernel(
    const float* __restrict__ Wf2, u16* __restrict__ outp)
{
    int e = blockIdx.x * 256 + threadIdx.x;      // 0..6143 (128*48)
    if (e >= 128 * 48) return;
    int k = e / 48, n = e - k * 48;
    float v = (n < ODIM) ? Wf2[k * ODIM + n] : 0.f;
    int nt = n >> 4, ks = k >> 5, q = (k >> 3) & 3, j = k & 7;
    outp[(((nt * 4 + ks) * 64 + q * 16 + (n & 15)) << 3) + j] = f_to_bf16(v);
}

// ---------------------------------------------------------------------------
// Mean-gather on bf16 features, one wave per node.
// ---------------------------------------------------------------------------
__global__ __launch_bounds__(256) void gather_mean16_kernel(
    const u32* __restrict__ feat,    // [N][64] u32 (=128 bf16)
    const int* __restrict__ cs, const int* __restrict__ pc, const int* __restrict__ ic,
    u32* __restrict__ A)             // [N][64] u32
{
    const int wave = threadIdx.x >> 6;
    const int lane = threadIdx.x & 63;
    const int node = blockIdx.x * 4 + wave;
    const int end  = pc[node];
    const int deg  = ic[node];
    const int start = end - deg;

    float ax = 0.f, ay = 0.f;
    for (int b = start; b < end; b += 64) {
        int m = end - b; if (m > 64) m = 64;
        int idx = cs[b + (lane < m ? lane : 0)];
        for (int j = 0; j < m; ++j) {
            int s = __shfl(idx, j, 64);
            u32 v = feat[((size_t)s << 6) + lane];
            ax += bf16lo_to_f(v);
            ay += bf16hi_to_f(v);
        }
    }
    float inv = 1.0f / (float)(deg > 0 ? deg : 1);
    A[((size_t)node << 6) + lane] = pack_bf16x2(ax * inv, ay * inv);
}

// ---------------------------------------------------------------------------
// MFMA dual GEMM: out = [relu]( A1 @ W1 + bias [+ A2 @ W2] )
// ---------------------------------------------------------------------------
__global__ __launch_bounds__(256) void mfma_gemm_kernel(
    const u16* __restrict__ A1, const u16* __restrict__ A2,
    const u16* __restrict__ W1p, const u16* __restrict__ W2p,
    const float* __restrict__ bias,
    u16* __restrict__ out16, float* __restrict__ out32, int do_relu)
{
    __shared__ u16 sAll[2 * 8192];    // 2 x 64x128 bf16 = 32 KB, frag order
    const int tid  = threadIdx.x;
    const int base = blockIdx.x * 64;
    const int nmats = (A2 != nullptr) ? 2 : 1;

    for (int mat = 0; mat < nmats; ++mat) {
        const u16* Ain = mat ? A2 : A1;
        u16* sDst = &sAll[mat * 8192];
        for (int it = 0; it < 4; ++it) {
            int c   = it * 256 + tid;
            int row = c >> 4;
            int ch8 = c & 15;
            int rowg = base + row; if (rowg > N_NODES - 1) rowg = N_NODES - 1;
            uint4 v = *reinterpret_cast<const uint4*>(Ain + ((size_t)rowg << 7) + (ch8 << 3));
            int q = ch8 & 3, ks = ch8 >> 2;
            int dc = ((row >> 4) * 4 + ks) * 64 + q * 16 + (row & 15);
            *reinterpret_cast<uint4*>(sDst + (dc << 3)) = v;
        }
    }
    __syncthreads();

    const int wave = tid >> 6;
    const int lane = tid & 63;

    f32x4 acc[8];
    #pragma unroll
    for (int nt = 0; nt < 8; ++nt) acc[nt] = (f32x4){0.f, 0.f, 0.f, 0.f};

    for (int mat = 0; mat < nmats; ++mat) {
        const u16* Wp = mat ? W2p : W1p;
        const u16* sA = &sAll[mat * 8192];
        #pragma unroll
        for (int ks = 0; ks < 4; ++ks) {
            bf16x8 a = *reinterpret_cast<const bf16x8*>(sA + (((wave * 4 + ks) * 64 + lane) << 3));
            #pragma unroll
            for (int nt = 0; nt < 8; ++nt) {
                bf16x8 b = *reinterpret_cast<const bf16x8*>(Wp + (((nt * 4 + ks) * 64 + lane) << 3));
                acc[nt] = __builtin_amdgcn_mfma_f32_16x16x32_bf16(a, b, acc[nt], 0, 0, 0);
            }
        }
    }

    const int m = lane & 15;
    const int q = lane >> 4;
    #pragma unroll
    for (int nt = 0; nt < 8; ++nt) {
        int col = nt * 16 + m;
        float bv = bias[col];
        #pragma unroll
        for (int r = 0; r < 4; ++r) {
            int rowg = base + wave * 16 + q * 4 + r;
            if (rowg >= N_NODES) continue;
            float v = acc[nt][r] + bv;
            if (do_relu) v = fmaxf(v, 0.f);
            if (out16) out16[((size_t)rowg << 7) + col] = f_to_bf16(v);
            if (out32) out32[((size_t)rowg << 7) + col] = v;
        }
    }
}

// ---------------------------------------------------------------------------
// Head: z = t @ Wf2 + bf2 (128->40, MFMA on 48-padded cols), then row-wise
// log_softmax entirely in registers via quad-local shuffle reductions.
// D layout per 16x16 tile: lane holds rows q*4+r, col nt*16+m.
// Row-reduction = butterfly over the 16 lanes of each quad (width=16).
// ---------------------------------------------------------------------------
__global__ __launch_bounds__(256) void mfma_softmax_kernel(
    const u16* __restrict__ t,       // bf16 [N][128]
    const u16* __restrict__ Wf2p,    // packed 128x48 B-frags
    const float* __restrict__ bf2,
    float* __restrict__ out)         // [N][40]
{
    __shared__ u16 sA[8192];         // 64x128 bf16, A-frag order (16 KB)
    const int tid  = threadIdx.x;
    const int base = blockIdx.x * 64;

    for (int it = 0; it < 4; ++it) {
        int c   = it * 256 + tid;
        int row = c >> 4;
        int ch8 = c & 15;
        int rowg = base + row; if (rowg > N_NODES - 1) rowg = N_NODES - 1;
        uint4 v = *reinterpret_cast<const uint4*>(t + ((size_t)rowg << 7) + (ch8 << 3));
        int q = ch8 & 3, ks = ch8 >> 2;
        int dc = ((row >> 4) * 4 + ks) * 64 + q * 16 + (row & 15);
        *reinterpret_cast<uint4*>(sA + (dc << 3)) = v;
    }
    __syncthreads();

    const int wave = tid >> 6;
    const int lane = tid & 63;

    f32x4 acc[3];
    #pragma unroll
    for (int nt = 0; nt < 3; ++nt) acc[nt] = (f32x4){0.f, 0.f, 0.f, 0.f};

    #pragma unroll
    for (int ks = 0; ks < 4; ++ks) {
        bf16x8 a = *reinterpret_cast<const bf16x8*>(sA + (((wave * 4 + ks) * 64 + lane) << 3));
        #pragma unroll
        for (int nt = 0; nt < 3; ++nt) {
            bf16x8 b = *reinterpret_cast<const bf16x8*>(Wf2p + (((nt * 4 + ks) * 64 + lane) << 3));
            acc[nt] = __builtin_amdgcn_mfma_f32_16x16x32_bf16(a, b, acc[nt], 0, 0, 0);
        }
    }

    const int m = lane & 15;
    const int q = lane >> 4;

    float z[3][4];
    float mx[4] = {-INFINITY, -INFINITY, -INFINITY, -INFINITY};
    #pragma unroll
    for (int nt = 0; nt < 3; ++nt) {
        int col = nt * 16 + m;
        bool valid = (col < ODIM);
        float bv = valid ? bf2[col] : 0.f;
        #pragma unroll
        for (int r = 0; r < 4; ++r) {
            z[nt][r] = acc[nt][r] + bv;
            if (valid) mx[r] = fmaxf(mx[r], z[nt][r]);
        }
    }
    #pragma unroll
    for (int off = 1; off < 16; off <<= 1) {
        #pragma unroll
        for (int r = 0; r < 4; ++r) mx[r] = fmaxf(mx[r], __shfl_xor(mx[r], off, 16));
    }
    float sum[4] = {0.f, 0.f, 0.f, 0.f};
    #pragma unroll
    for (int nt = 0; nt < 3; ++nt) {
        int col = nt * 16 + m;
        if (col < ODIM) {
            #pragma unroll
            for (int r = 0; r < 4; ++r) sum[r] += expf(z[nt][r] - mx[r]);
        }
    }
    #pragma unroll
    for (int off = 1; off < 16; off <<= 1) {
        #pragma unroll
        for (int r = 0; r < 4; ++r) sum[r] += __shfl_xor(sum[r], off, 16);
    }
    float lse[4];
    #pragma unroll
    for (int r = 0; r < 4; ++r) lse[r] = logf(sum[r]) + mx[r];

    #pragma unroll
    for (int nt = 0; nt < 3; ++nt) {
        int col = nt * 16 + m;
        if (col >= ODIM) continue;
        #pragma unroll
        for (int r = 0; r < 4; ++r) {
            int rowg = base + wave * 16 + q * 4 + r;
            if (rowg >= N_NODES) continue;
            out[(size_t)rowg * ODIM + col] = z[nt][r] - lse[r];
        }
    }
}

// ---------------------------------------------------------------------------
extern "C" void kernel_launch(void* const* d_in, const int* in_sizes, int n_in,
                              void* d_out, int out_size, void* d_ws, size_t ws_size,
                              hipStream_t stream) {
    const float* x   = (const float*)d_in[0];
    const int*   ei  = (const int*)d_in[1];
    const int E = in_sizes[1] / 2;
    const int* src = ei;
    const int* dst = ei + E;

    const float* W1l = (const float*)d_in[2];
    const float* b1  = (const float*)d_in[3];
    const float* W1r = (const float*)d_in[4];
    const float* W2l = (const float*)d_in[5];
    const float* b2  = (const float*)d_in[6];
    const float* W2r = (const float*)d_in[7];
    const float* W3l = (const float*)d_in[8];
    const float* b3  = (const float*)d_in[9];
    const float* W3r = (const float*)d_in[10];
    const float* Wf1 = (const float*)d_in[11];
    const float* bf1 = (const float*)d_in[12];
    const float* Wf2 = (const float*)d_in[13];
    const float* bf2 = (const float*)d_in[14];

    float* out     = (float*)d_out;
    float* outTail = out + (size_t)N_NODES * ODIM;   // tuple part 2: h [N,128] fp32

    // CSR arrays live in d_out HEAD (16 MB; overwritten by final softmax,
    // which launches after the last CSR use).
    int* ic = (int*)out;            // 100352 ints
    int* pc = ic + 100352;          // 100352 ints
    int* bs = pc + 100352;          // 1024 ints
    int* cs = bs + 1024;            // E ints  (total ~3.4 MB)

    // Workspace (u16 units): X16 | F16a | F16b | A16 | Wpk(7x16384) | Wf2p
    const size_t FEAT16 = (size_t)N_NODES * HDIM;   // 12.8M u16 = 25.6 MB
    u16* X16  = (u16*)d_ws;
    u16* F16a = X16  + FEAT16;
    u16* F16b = F16a + FEAT16;
    u16* A16  = F16b + FEAT16;
    u16* Wpk  = A16  + FEAT16;                      // 7*16384 u16
    u16* Wp_1l = Wpk + 0 * 16384;
    u16* Wp_1r = Wpk + 1 * 16384;
    u16* Wp_2l = Wpk + 2 * 16384;
    u16* Wp_2r = Wpk + 3 * 16384;
    u16* Wp_3l = Wpk + 4 * 16384;
    u16* Wp_3r = Wpk + 5 * 16384;
    u16* Wp_f1 = Wpk + 6 * 16384;
    u16* Wf2p  = Wpk + 7 * 16384;                   // 6144 u16

    const int gemmGrid   = (N_NODES + 63) / 64;   // 1563
    const int gatherGrid = N_NODES / 4;           // 25000
    const int edgeGrid   = (E + 255) / 256;       // 2500
    const int cvtGrid    = (N_NODES * HDIM / 2 + 255) / 256;  // 25000

    // ---- CSR build ----
    hipMemsetAsync(ic, 0, N_NODES * sizeof(int), stream);
    count_deg_kernel<<<edgeGrid, 256, 0, stream>>>(dst, ic, E);
    block_sum_kernel<<<NBLK, 256, 0, stream>>>(ic, bs, N_NODES);
    scan_bs_kernel<<<1, 512, 0, stream>>>(bs, NBLK);
    scan_block_kernel<<<NBLK, 256, 0, stream>>>(ic, bs, pc, N_NODES);
    fill_kernel<<<edgeGrid, 256, 0, stream>>>(src, dst, pc, cs, E);

    // ---- prep: x -> bf16, pack weights ----
    f2bf_kernel<<<cvtGrid, 256, 0, stream>>>((const float2*)x, (u32*)X16, N_NODES * HDIM / 2);
    WPtrs wp; wp.w[0] = W1l; wp.w[1] = W1r; wp.w[2] = W2l; wp.w[3] = W2r;
    wp.w[4] = W3l; wp.w[5] = W3r; wp.w[6] = Wf1;
    pack_w_kernel<<<dim3(64, 7), 256, 0, stream>>>(wp, Wpk);
    pack_wf2_kernel<<<24, 256, 0, stream>>>(Wf2, Wf2p);

    // ---- layer 1: X16 -> F16a ----
    gather_mean16_kernel<<<gatherGrid, 256, 0, stream>>>((const u32*)X16, cs, pc, ic, (u32*)A16);
    mfma_gemm_kernel<<<gemmGrid, 256, 0, stream>>>(A16, X16, Wp_1l, Wp_1r, b1, F16a, nullptr, 1);

    // ---- layer 2: F16a -> F16b ----
    gather_mean16_kernel<<<gatherGrid, 256, 0, stream>>>((const u32*)F16a, cs, pc, ic, (u32*)A16);
    mfma_gemm_kernel<<<gemmGrid, 256, 0, stream>>>(A16, F16a, Wp_2l, Wp_2r, b2, F16b, nullptr, 1);

    // ---- layer 3: F16b -> F16a (bf16) + outTail (fp32 h3), no relu ----
    gather_mean16_kernel<<<gatherGrid, 256, 0, stream>>>((const u32*)F16b, cs, pc, ic, (u32*)A16);
    mfma_gemm_kernel<<<gemmGrid, 256, 0, stream>>>(A16, F16b, Wp_3l, Wp_3r, b3, F16a, outTail, 0);

    // ---- MLP head: t = relu(h3 @ Wf1 + bf1) -> A16 (bf16) ----
    mfma_gemm_kernel<<<gemmGrid, 256, 0, stream>>>(F16a, nullptr, Wp_f1, nullptr, bf1, A16, nullptr, 1);

    // ---- z = t @ Wf2 + bf2, log_softmax -> out head (overwrites CSR debris) ----
    mfma_softmax_kernel<<<gemmGrid, 256, 0, stream>>>(A16, Wf2p, bf2, out);
}

// Round 6
// 467.918 us; speedup vs baseline: 8.3285x; 1.1164x over previous
//
#include <hip/hip_runtime.h>
#include <math.h>

#define N_NODES 100000
#define HDIM    128
#define ODIM    40
#define NBLK    ((N_NODES + 255) / 256)   // 391

typedef unsigned short u16;
typedef unsigned int   u32;
typedef short bf16x8 __attribute__((ext_vector_type(8)));   // 8 bf16 in 4 VGPRs
typedef float f32x4  __attribute__((ext_vector_type(4)));

// ---------------- bf16 helpers ----------------
__device__ inline float bf16lo_to_f(u32 v) {
    u32 u = v << 16; float f; __builtin_memcpy(&f, &u, 4); return f;
}
__device__ inline float bf16hi_to_f(u32 v) {
    u32 u = v & 0xffff0000u; float f; __builtin_memcpy(&f, &u, 4); return f;
}
__device__ inline u16 f_to_bf16(float f) {
    u32 u; __builtin_memcpy(&u, &f, 4);
    u32 r = (u + 0x7fffu + ((u >> 16) & 1u)) >> 16;   // round-nearest-even
    return (u16)r;
}
__device__ inline u32 pack_bf16x2(float a, float b) {
    return (u32)f_to_bf16(a) | ((u32)f_to_bf16(b) << 16);
}

// ---------------------------------------------------------------------------
// CSR build (counting sort by dst).
// ---------------------------------------------------------------------------
__global__ __launch_bounds__(256) void count_deg_kernel(
    const int* __restrict__ dst, int* __restrict__ ic, int E)
{
    int e = blockIdx.x * 256 + threadIdx.x;
    if (e < E) atomicAdd(ic + dst[e], 1);
}

__global__ __launch_bounds__(256) void block_sum_kernel(
    const int* __restrict__ ic, int* __restrict__ bs, int n)
{
    __shared__ int sm[256];
    int t = threadIdx.x;
    int i = blockIdx.x * 256 + t;
    sm[t] = (i < n) ? ic[i] : 0;
    __syncthreads();
    for (int s = 128; s > 0; s >>= 1) {
        if (t < s) sm[t] += sm[t + s];
        __syncthreads();
    }
    if (t == 0) bs[blockIdx.x] = sm[0];
}

__global__ __launch_bounds__(512) void scan_bs_kernel(int* __restrict__ bs, int nb)
{
    __shared__ int sm[512];
    int t = threadIdx.x;
    sm[t] = (t < nb) ? bs[t] : 0;
    __syncthreads();
    for (int off = 1; off < 512; off <<= 1) {
        int v = (t >= off) ? sm[t - off] : 0;
        __syncthreads();
        sm[t] += v;
        __syncthreads();
    }
    if (t < nb) bs[t] = (t == 0) ? 0 : sm[t - 1];
}

__global__ __launch_bounds__(256) void scan_block_kernel(
    const int* __restrict__ ic, const int* __restrict__ bs,
    int* __restrict__ pc, int n)
{
    __shared__ int sm[256];
    int t = threadIdx.x;
    int i = blockIdx.x * 256 + t;
    int v = (i < n) ? ic[i] : 0;
    sm[t] = v;
    __syncthreads();
    for (int off = 1; off < 256; off <<= 1) {
        int u = (t >= off) ? sm[t - off] : 0;
        __syncthreads();
        sm[t] += u;
        __syncthreads();
    }
    if (i < n) pc[i] = bs[blockIdx.x] + sm[t] - v;   // exclusive
}

__global__ __launch_bounds__(256) void fill_kernel(
    const int* __restrict__ src, const int* __restrict__ dst,
    int* __restrict__ pc, int* __restrict__ cs, int E)
{
    int e = blockIdx.x * 256 + threadIdx.x;
    if (e < E) {
        int p = atomicAdd(pc + dst[e], 1);
        cs[p] = src[e];
    }
}
// after fill: end(n) = pc[n], start(n) = pc[n] - ic[n]

// ---------------------------------------------------------------------------
// fp32 -> bf16 feature conversion (2 elements / thread).
// ---------------------------------------------------------------------------
__global__ __launch_bounds__(256) void f2bf_kernel(
    const float2* __restrict__ in, u32* __restrict__ out, int n2)
{
    int i = blockIdx.x * 256 + threadIdx.x;
    if (i < n2) { float2 v = in[i]; out[i] = pack_bf16x2(v.x, v.y); }
}

// ---------------------------------------------------------------------------
// Pack 128x128 fp32 weight matrices into bf16 MFMA B-fragment order:
//   frag (ntile, kslice): 64 lanes x 8 bf16, lane = q*16 + (n&15),
//   element j: B[k = kslice*32 + q*8 + j][n = ntile*16 + (n&15)]
// ---------------------------------------------------------------------------
struct WPtrs { const float* w[7]; };

__global__ __launch_bounds__(256) void pack_w_kernel(WPtrs p, u16* __restrict__ out)
{
    int mat = blockIdx.y;
    int e = blockIdx.x * 256 + threadIdx.x;      // 0..16383
    int k = e >> 7, n = e & 127;
    float v = p.w[mat][e];
    int nt = n >> 4, ks = k >> 5, q = (k >> 3) & 3, j = k & 7;
    int dst = mat * 16384 + (((nt * 4 + ks) * 64 + q * 16 + (n & 15)) << 3) + j;
    out[dst] = f_to_bf16(v);
}

// Pack Wf2 [128][40] into 128x48 (zero-padded) B-frag order: 3 ntiles x 4 ks.
__global__ __launch_bounds__(256) void pack_wf2_kernel(
    const float* __restrict__ Wf2, u16* __restrict__ outp)
{
    int e = blockIdx.x * 256 + threadIdx.x;      // 0..6143 (128*48)
    if (e >= 128 * 48) return;
    int k = e / 48, n = e - k * 48;
    float v = (n < ODIM) ? Wf2[k * ODIM + n] : 0.f;
    int nt = n >> 4, ks = k >> 5, q = (k >> 3) & 3, j = k & 7;
    outp[(((nt * 4 + ks) * 64 + q * 16 + (n & 15)) << 3) + j] = f_to_bf16(v);
}

// ---------------------------------------------------------------------------
// Mean-gather on bf16 features, one wave per node, 4-way neighbor ILP:
// lanes = 4 groups x 16; group g loads neighbor (j+g)'s row as dwordx4
// (16 B/lane, 1 KB/instruction). Indices preloaded per 64-batch and
// distributed via per-lane __shfl (ds_bpermute). Partial sums combined with
// shfl_xor butterflies at the end; lanes 0-15 write the mean row.
// ---------------------------------------------------------------------------
__global__ __launch_bounds__(256) void gather_mean16_kernel(
    const u32* __restrict__ feat,    // [N][64] u32 (=128 bf16)
    const int* __restrict__ cs, const int* __restrict__ pc, const int* __restrict__ ic,
    u32* __restrict__ A)             // [N][64] u32
{
    const int wave = threadIdx.x >> 6;
    const int lane = threadIdx.x & 63;
    const int node = blockIdx.x * 4 + wave;
    const int end  = pc[node];
    const int deg  = ic[node];
    const int start = end - deg;
    const int g    = lane >> 4;       // neighbor sub-slot 0..3
    const int ch   = lane & 15;       // 16B chunk 0..15 within the row

    float acc[8] = {0.f,0.f,0.f,0.f,0.f,0.f,0.f,0.f};

    for (int b = start; b < end; b += 64) {
        int m = end - b; if (m > 64) m = 64;
        int idxv = cs[b + (lane < m ? lane : 0)];
        for (int j = 0; j < m; j += 4) {
            int nb = j + g;
            int s  = __shfl(idxv, nb, 64);
            uint4 v = {0u, 0u, 0u, 0u};
            if (nb < m)
                v = *reinterpret_cast<const uint4*>(feat + ((size_t)s << 6) + (ch << 2));
            acc[0] += bf16lo_to_f(v.x); acc[1] += bf16hi_to_f(v.x);
            acc[2] += bf16lo_to_f(v.y); acc[3] += bf16hi_to_f(v.y);
            acc[4] += bf16lo_to_f(v.z); acc[5] += bf16hi_to_f(v.z);
            acc[6] += bf16lo_to_f(v.w); acc[7] += bf16hi_to_f(v.w);
        }
    }

    #pragma unroll
    for (int off = 16; off < 64; off <<= 1) {
        #pragma unroll
        for (int k = 0; k < 8; ++k) acc[k] += __shfl_xor(acc[k], off, 64);
    }

    if (lane < 16) {
        float inv = 1.0f / (float)(deg > 0 ? deg : 1);
        uint4 o;
        o.x = pack_bf16x2(acc[0] * inv, acc[1] * inv);
        o.y = pack_bf16x2(acc[2] * inv, acc[3] * inv);
        o.z = pack_bf16x2(acc[4] * inv, acc[5] * inv);
        o.w = pack_bf16x2(acc[6] * inv, acc[7] * inv);
        *reinterpret_cast<uint4*>(A + ((size_t)node << 6) + (ch << 2)) = o;
    }
}

// ---------------------------------------------------------------------------
// MFMA dual GEMM: out = [relu]( A1 @ W1 + bias [+ A2 @ W2] )
// ---------------------------------------------------------------------------
__global__ __launch_bounds__(256) void mfma_gemm_kernel(
    const u16* __restrict__ A1, const u16* __restrict__ A2,
    const u16* __restrict__ W1p, const u16* __restrict__ W2p,
    const float* __restrict__ bias,
    u16* __restrict__ out16, float* __restrict__ out32, int do_relu)
{
    __shared__ u16 sAll[2 * 8192];    // 2 x 64x128 bf16 = 32 KB, frag order
    const int tid  = threadIdx.x;
    const int base = blockIdx.x * 64;
    const int nmats = (A2 != nullptr) ? 2 : 1;

    for (int mat = 0; mat < nmats; ++mat) {
        const u16* Ain = mat ? A2 : A1;
        u16* sDst = &sAll[mat * 8192];
        for (int it = 0; it < 4; ++it) {
            int c   = it * 256 + tid;
            int row = c >> 4;
            int ch8 = c & 15;
            int rowg = base + row; if (rowg > N_NODES - 1) rowg = N_NODES - 1;
            uint4 v = *reinterpret_cast<const uint4*>(Ain + ((size_t)rowg << 7) + (ch8 << 3));
            int q = ch8 & 3, ks = ch8 >> 2;
            int dc = ((row >> 4) * 4 + ks) * 64 + q * 16 + (row & 15);
            *reinterpret_cast<uint4*>(sDst + (dc << 3)) = v;
        }
    }
    __syncthreads();

    const int wave = tid >> 6;
    const int lane = tid & 63;

    f32x4 acc[8];
    #pragma unroll
    for (int nt = 0; nt < 8; ++nt) acc[nt] = (f32x4){0.f, 0.f, 0.f, 0.f};

    for (int mat = 0; mat < nmats; ++mat) {
        const u16* Wp = mat ? W2p : W1p;
        const u16* sA = &sAll[mat * 8192];
        #pragma unroll
        for (int ks = 0; ks < 4; ++ks) {
            bf16x8 a = *reinterpret_cast<const bf16x8*>(sA + (((wave * 4 + ks) * 64 + lane) << 3));
            #pragma unroll
            for (int nt = 0; nt < 8; ++nt) {
                bf16x8 b = *reinterpret_cast<const bf16x8*>(Wp + (((nt * 4 + ks) * 64 + lane) << 3));
                acc[nt] = __builtin_amdgcn_mfma_f32_16x16x32_bf16(a, b, acc[nt], 0, 0, 0);
            }
        }
    }

    const int m = lane & 15;
    const int q = lane >> 4;
    #pragma unroll
    for (int nt = 0; nt < 8; ++nt) {
        int col = nt * 16 + m;
        float bv = bias[col];
        #pragma unroll
        for (int r = 0; r < 4; ++r) {
            int rowg = base + wave * 16 + q * 4 + r;
            if (rowg >= N_NODES) continue;
            float v = acc[nt][r] + bv;
            if (do_relu) v = fmaxf(v, 0.f);
            if (out16) out16[((size_t)rowg << 7) + col] = f_to_bf16(v);
            if (out32) out32[((size_t)rowg << 7) + col] = v;
        }
    }
}

// ---------------------------------------------------------------------------
// Head: z = t @ Wf2 + bf2 (128->40, MFMA on 48-padded cols), then row-wise
// log_softmax entirely in registers via quad-local shuffle reductions.
// ---------------------------------------------------------------------------
__global__ __launch_bounds__(256) void mfma_softmax_kernel(
    const u16* __restrict__ t,       // bf16 [N][128]
    const u16* __restrict__ Wf2p,    // packed 128x48 B-frags
    const float* __restrict__ bf2,
    float* __restrict__ out)         // [N][40]
{
    __shared__ u16 sA[8192];         // 64x128 bf16, A-frag order (16 KB)
    const int tid  = threadIdx.x;
    const int base = blockIdx.x * 64;

    for (int it = 0; it < 4; ++it) {
        int c   = it * 256 + tid;
        int row = c >> 4;
        int ch8 = c & 15;
        int rowg = base + row; if (rowg > N_NODES - 1) rowg = N_NODES - 1;
        uint4 v = *reinterpret_cast<const uint4*>(t + ((size_t)rowg << 7) + (ch8 << 3));
        int q = ch8 & 3, ks = ch8 >> 2;
        int dc = ((row >> 4) * 4 + ks) * 64 + q * 16 + (row & 15);
        *reinterpret_cast<uint4*>(sA + (dc << 3)) = v;
    }
    __syncthreads();

    const int wave = tid >> 6;
    const int lane = tid & 63;

    f32x4 acc[3];
    #pragma unroll
    for (int nt = 0; nt < 3; ++nt) acc[nt] = (f32x4){0.f, 0.f, 0.f, 0.f};

    #pragma unroll
    for (int ks = 0; ks < 4; ++ks) {
        bf16x8 a = *reinterpret_cast<const bf16x8*>(sA + (((wave * 4 + ks) * 64 + lane) << 3));
        #pragma unroll
        for (int nt = 0; nt < 3; ++nt) {
            bf16x8 b = *reinterpret_cast<const bf16x8*>(Wf2p + (((nt * 4 + ks) * 64 + lane) << 3));
            acc[nt] = __builtin_amdgcn_mfma_f32_16x16x32_bf16(a, b, acc[nt], 0, 0, 0);
        }
    }

    const int m = lane & 15;
    const int q = lane >> 4;

    float z[3][4];
    float mx[4] = {-INFINITY, -INFINITY, -INFINITY, -INFINITY};
    #pragma unroll
    for (int nt = 0; nt < 3; ++nt) {
        int col = nt * 16 + m;
        bool valid = (col < ODIM);
        float bv = valid ? bf2[col] : 0.f;
        #pragma unroll
        for (int r = 0; r < 4; ++r) {
            z[nt][r] = acc[nt][r] + bv;
            if (valid) mx[r] = fmaxf(mx[r], z[nt][r]);
        }
    }
    #pragma unroll
    for (int off = 1; off < 16; off <<= 1) {
        #pragma unroll
        for (int r = 0; r < 4; ++r) mx[r] = fmaxf(mx[r], __shfl_xor(mx[r], off, 16));
    }
    float sum[4] = {0.f, 0.f, 0.f, 0.f};
    #pragma unroll
    for (int nt = 0; nt < 3; ++nt) {
        int col = nt * 16 + m;
        if (col < ODIM) {
            #pragma unroll
            for (int r = 0; r < 4; ++r) sum[r] += expf(z[nt][r] - mx[r]);
        }
    }
    #pragma unroll
    for (int off = 1; off < 16; off <<= 1) {
        #pragma unroll
        for (int r = 0; r < 4; ++r) sum[r] += __shfl_xor(sum[r], off, 16);
    }
    float lse[4];
    #pragma unroll
    for (int r = 0; r < 4; ++r) lse[r] = logf(sum[r]) + mx[r];

    #pragma unroll
    for (int nt = 0; nt < 3; ++nt) {
        int col = nt * 16 + m;
        if (col >= ODIM) continue;
        #pragma unroll
        for (int r = 0; r < 4; ++r) {
            int rowg = base + wave * 16 + q * 4 + r;
            if (rowg >= N_NODES) continue;
            out[(size_t)rowg * ODIM + col] = z[nt][r] - lse[r];
        }
    }
}

// ---------------------------------------------------------------------------
extern "C" void kernel_launch(void* const* d_in, const int* in_sizes, int n_in,
                              void* d_out, int out_size, void* d_ws, size_t ws_size,
                              hipStream_t stream) {
    const float* x   = (const float*)d_in[0];
    const int*   ei  = (const int*)d_in[1];
    const int E = in_sizes[1] / 2;
    const int* src = ei;
    const int* dst = ei + E;

    const float* W1l = (const float*)d_in[2];
    const float* b1  = (const float*)d_in[3];
    const float* W1r = (const float*)d_in[4];
    const float* W2l = (const float*)d_in[5];
    const float* b2  = (const float*)d_in[6];
    const float* W2r = (const float*)d_in[7];
    const float* W3l = (const float*)d_in[8];
    const float* b3  = (const float*)d_in[9];
    const float* W3r = (const float*)d_in[10];
    const float* Wf1 = (const float*)d_in[11];
    const float* bf1 = (const float*)d_in[12];
    const float* Wf2 = (const float*)d_in[13];
    const float* bf2 = (const float*)d_in[14];

    float* out     = (float*)d_out;
    float* outTail = out + (size_t)N_NODES * ODIM;   // tuple part 2: h [N,128] fp32

    // CSR arrays live in d_out HEAD (16 MB; overwritten by final softmax,
    // which launches after the last CSR use).
    int* ic = (int*)out;            // 100352 ints
    int* pc = ic + 100352;          // 100352 ints
    int* bs = pc + 100352;          // 1024 ints
    int* cs = bs + 1024;            // E ints  (total ~3.4 MB)

    // Workspace (u16 units): X16 | F16a | F16b | A16 | Wpk(7x16384) | Wf2p
    const size_t FEAT16 = (size_t)N_NODES * HDIM;   // 12.8M u16 = 25.6 MB
    u16* X16  = (u16*)d_ws;
    u16* F16a = X16  + FEAT16;
    u16* F16b = F16a + FEAT16;
    u16* A16  = F16b + FEAT16;
    u16* Wpk  = A16  + FEAT16;                      // 7*16384 u16
    u16* Wp_1l = Wpk + 0 * 16384;
    u16* Wp_1r = Wpk + 1 * 16384;
    u16* Wp_2l = Wpk + 2 * 16384;
    u16* Wp_2r = Wpk + 3 * 16384;
    u16* Wp_3l = Wpk + 4 * 16384;
    u16* Wp_3r = Wpk + 5 * 16384;
    u16* Wp_f1 = Wpk + 6 * 16384;
    u16* Wf2p  = Wpk + 7 * 16384;                   // 6144 u16

    const int gemmGrid   = (N_NODES + 63) / 64;   // 1563
    const int gatherGrid = N_NODES / 4;           // 25000
    const int edgeGrid   = (E + 255) / 256;       // 2500
    const int cvtGrid    = (N_NODES * HDIM / 2 + 255) / 256;  // 25000

    // ---- CSR build ----
    hipMemsetAsync(ic, 0, N_NODES * sizeof(int), stream);
    count_deg_kernel<<<edgeGrid, 256, 0, stream>>>(dst, ic, E);
    block_sum_kernel<<<NBLK, 256, 0, stream>>>(ic, bs, N_NODES);
    scan_bs_kernel<<<1, 512, 0, stream>>>(bs, NBLK);
    scan_block_kernel<<<NBLK, 256, 0, stream>>>(ic, bs, pc, N_NODES);
    fill_kernel<<<edgeGrid, 256, 0, stream>>>(src, dst, pc, cs, E);

    // ---- prep: x -> bf16, pack weights ----
    f2bf_kernel<<<cvtGrid, 256, 0, stream>>>((const float2*)x, (u32*)X16, N_NODES * HDIM / 2);
    WPtrs wp; wp.w[0] = W1l; wp.w[1] = W1r; wp.w[2] = W2l; wp.w[3] = W2r;
    wp.w[4] = W3l; wp.w[5] = W3r; wp.w[6] = Wf1;
    pack_w_kernel<<<dim3(64, 7), 256, 0, stream>>>(wp, Wpk);
    pack_wf2_kernel<<<24, 256, 0, stream>>>(Wf2, Wf2p);

    // ---- layer 1: X16 -> F16a ----
    gather_mean16_kernel<<<gatherGrid, 256, 0, stream>>>((const u32*)X16, cs, pc, ic, (u32*)A16);
    mfma_gemm_kernel<<<gemmGrid, 256, 0, stream>>>(A16, X16, Wp_1l, Wp_1r, b1, F16a, nullptr, 1);

    // ---- layer 2: F16a -> F16b ----
    gather_mean16_kernel<<<gatherGrid, 256, 0, stream>>>((const u32*)F16a, cs, pc, ic, (u32*)A16);
    mfma_gemm_kernel<<<gemmGrid, 256, 0, stream>>>(A16, F16a, Wp_2l, Wp_2r, b2, F16b, nullptr, 1);

    // ---- layer 3: F16b -> F16a (bf16) + outTail (fp32 h3), no relu ----
    gather_mean16_kernel<<<gatherGrid, 256, 0, stream>>>((const u32*)F16b, cs, pc, ic, (u32*)A16);
    mfma_gemm_kernel<<<gemmGrid, 256, 0, stream>>>(A16, F16b, Wp_3l, Wp_3r, b3, F16a, outTail, 0);

    // ---- MLP head: t = relu(h3 @ Wf1 + bf1) -> A16 (bf16) ----
    mfma_gemm_kernel<<<gemmGrid, 256, 0, stream>>>(F16a, nullptr, Wp_f1, nullptr, bf1, A16, nullptr, 1);

    // ---- z = t @ Wf2 + bf2, log_softmax -> out head (overwrites CSR debris) ----
    mfma_softmax_kernel<<<gemmGrid, 256, 0, stream>>>(A16, Wf2p, bf2, out);
}